// Round 1
// baseline (1889.554 us; speedup 1.0000x reference)
//
#include <hip/hip_runtime.h>

#define IN_DIM 128
#define HID 64
#define OUT_DIM 128
#define NGRAPH 8

// ---------------- degree accumulation ----------------
__global__ void deg_kernel(const int* __restrict__ dst, const float* __restrict__ ew,
                           float* __restrict__ deg, int E) {
    int i = blockIdx.x * blockDim.x + threadIdx.x;
    if (i < E) atomicAdd(&deg[dst[i]], ew[i]);
}

// deg -> dinv = rsqrt(deg + 1)   (self-loop weight 1 always present => deg > 0)
__global__ void dinv_kernel(float* __restrict__ deg, int N) {
    int i = blockIdx.x * blockDim.x + threadIdx.x;
    if (i < N) deg[i] = rsqrtf(deg[i] + 1.0f);
}

// ---------------- layer 1 GEMM: h = x @ W1 ; agg = h * dinv^2 (self loop) ----
// one wave per row, lane = output col (HID = 64)
__global__ void gemm1_kernel(const float* __restrict__ x, const float* __restrict__ W1,
                             const float* __restrict__ dinv, float* __restrict__ h,
                             float* __restrict__ agg, int N) {
    int gid = blockIdx.x * blockDim.x + threadIdx.x;
    int row = gid >> 6, lane = gid & 63;
    if (row >= N) return;
    const float4* xr = reinterpret_cast<const float4*>(x + (size_t)row * IN_DIM);
    float acc = 0.f;
#pragma unroll
    for (int k4 = 0; k4 < IN_DIM / 4; ++k4) {
        float4 xv = xr[k4];
        int k = k4 * 4;
        acc += xv.x * W1[(k + 0) * HID + lane];
        acc += xv.y * W1[(k + 1) * HID + lane];
        acc += xv.z * W1[(k + 2) * HID + lane];
        acc += xv.w * W1[(k + 3) * HID + lane];
    }
    h[(size_t)row * HID + lane] = acc;
    float di = dinv[row];
    agg[(size_t)row * HID + lane] = acc * di * di;
}

// ---------------- edge aggregation: agg[dst] += h[src] * norm ----------------
// one wave per edge, lane = feature dim
__global__ void edge_kernel(const int* __restrict__ src, const int* __restrict__ dst,
                            const float* __restrict__ ew, const float* __restrict__ dinv,
                            const float* __restrict__ h, float* __restrict__ agg, int E) {
    int gid = blockIdx.x * blockDim.x + threadIdx.x;
    int e = gid >> 6, lane = gid & 63;
    if (e >= E) return;
    int s = src[e], d = dst[e];
    float norm = dinv[s] * ew[e] * dinv[d];
    atomicAdd(&agg[(size_t)d * HID + lane], h[(size_t)s * HID + lane] * norm);
}

// ---------------- layer 2 GEMM: h2 = relu(agg1 + b1) @ W2 --------------------
__global__ void gemm2_kernel(const float* __restrict__ agg1, const float* __restrict__ b1,
                             const float* __restrict__ W2, float* __restrict__ h2, int N) {
    int gid = blockIdx.x * blockDim.x + threadIdx.x;
    int row = gid >> 6, lane = gid & 63;
    if (row >= N) return;
    const float4* ar = reinterpret_cast<const float4*>(agg1 + (size_t)row * HID);
    const float4* bv4 = reinterpret_cast<const float4*>(b1);
    float acc = 0.f;
#pragma unroll
    for (int k4 = 0; k4 < HID / 4; ++k4) {
        float4 av = ar[k4];
        float4 bv = bv4[k4];
        int k = k4 * 4;
        float a0 = fmaxf(av.x + bv.x, 0.f);
        float a1 = fmaxf(av.y + bv.y, 0.f);
        float a2 = fmaxf(av.z + bv.z, 0.f);
        float a3 = fmaxf(av.w + bv.w, 0.f);
        acc += a0 * W2[(k + 0) * HID + lane];
        acc += a1 * W2[(k + 1) * HID + lane];
        acc += a2 * W2[(k + 2) * HID + lane];
        acc += a3 * W2[(k + 3) * HID + lane];
    }
    h2[(size_t)row * HID + lane] = acc;
}

// self-loop init for layer 2: agg2 = h2 * dinv^2  (plain store, runs after gemm2)
__global__ void selfloop_kernel(const float* __restrict__ h2, const float* __restrict__ dinv,
                                float* __restrict__ agg, int N) {
    int gid = blockIdx.x * blockDim.x + threadIdx.x;
    int row = gid >> 6, lane = gid & 63;
    if (row >= N) return;
    float di = dinv[row];
    agg[(size_t)row * HID + lane] = h2[(size_t)row * HID + lane] * di * di;
}

// ---------------- pooling: segment sum over sorted batch ---------------------
// one wave per contiguous node chunk; flush on batch-id change (rare: sorted)
__global__ void pool_kernel(const float* __restrict__ agg2, const int* __restrict__ batch,
                            float* __restrict__ pooled, float* __restrict__ cnt,
                            int N, int chunk) {
    int wid = (blockIdx.x * blockDim.x + threadIdx.x) >> 6;
    int lane = threadIdx.x & 63;
    int start = wid * chunk;
    if (start >= N) return;
    int end = min(start + chunk, N);
    float acc = 0.f, fc = 0.f;
    int cur = batch[start];
    for (int n = start; n < end; ++n) {
        int g = batch[n];
        if (g != cur) {
            atomicAdd(&pooled[cur * HID + lane], acc);
            if (lane == 0) atomicAdd(&cnt[cur], fc);
            cur = g; acc = 0.f; fc = 0.f;
        }
        acc += agg2[(size_t)n * HID + lane];
        fc += 1.f;
    }
    atomicAdd(&pooled[cur * HID + lane], acc);
    if (lane == 0) atomicAdd(&cnt[cur], fc);
}

// ---------------- final: out = (pooled/cnt + b2) @ Wfc + bfc -----------------
__global__ void final_kernel(const float* __restrict__ pooled, const float* __restrict__ cnt,
                             const float* __restrict__ b2, const float* __restrict__ Wfc,
                             const float* __restrict__ bfc, float* __restrict__ out) {
    int idx = blockIdx.x * blockDim.x + threadIdx.x;
    if (idx >= NGRAPH * OUT_DIM) return;
    int g = idx >> 7, o = idx & 127;
    float inv = 1.0f / fmaxf(cnt[g], 1.0f);
    float acc = 0.f;
#pragma unroll
    for (int k = 0; k < HID; ++k)
        acc += (pooled[g * HID + k] * inv + b2[k]) * Wfc[k * OUT_DIM + o];
    out[idx] = acc + bfc[o];
}

extern "C" void kernel_launch(void* const* d_in, const int* in_sizes, int n_in,
                              void* d_out, int out_size, void* d_ws, size_t ws_size,
                              hipStream_t stream) {
    const float* x    = (const float*)d_in[0];
    const int*   ei   = (const int*)d_in[1];
    const float* ew   = (const float*)d_in[2];
    const int*   bat  = (const int*)d_in[3];
    const float* W1   = (const float*)d_in[4];
    const float* b1   = (const float*)d_in[5];
    const float* W2   = (const float*)d_in[6];
    const float* b2   = (const float*)d_in[7];
    const float* Wfc  = (const float*)d_in[8];
    const float* bfc  = (const float*)d_in[9];
    float* out = (float*)d_out;

    const int N = in_sizes[0] / IN_DIM;
    const int E = in_sizes[2];
    const int* src = ei;
    const int* dst = ei + E;

    // workspace layout (256B aligned regions)
    char* ws = (char*)d_ws;
    size_t off = 0;
    float* deg = (float*)(ws + off);                       // N floats (becomes dinv)
    off += ((size_t)N * 4 + 255) / 256 * 256;
    float* pooled = (float*)(ws + off);                    // 8*64 floats
    float* cnt = pooled + NGRAPH * HID;                    // 8 floats
    off += ((NGRAPH * HID + NGRAPH) * 4 + 255) / 256 * 256;
    float* h = (float*)(ws + off);                         // N*64 floats (h1, then h2)
    off += (size_t)N * HID * 4;
    float* agg = (float*)(ws + off);                       // N*64 floats (agg1, then agg2)

    hipMemsetAsync(deg, 0, (size_t)N * 4, stream);
    hipMemsetAsync(pooled, 0, (NGRAPH * HID + NGRAPH) * 4, stream);

    // degree + normalization
    deg_kernel<<<(E + 255) / 256, 256, 0, stream>>>(dst, ew, deg, E);
    dinv_kernel<<<(N + 255) / 256, 256, 0, stream>>>(deg, N);

    // layer 1
    int rowBlocks = (int)(((size_t)N * 64 + 255) / 256);
    gemm1_kernel<<<rowBlocks, 256, 0, stream>>>(x, W1, deg, h, agg, N);
    int edgeBlocks = (int)(((size_t)E * 64 + 255) / 256);
    edge_kernel<<<edgeBlocks, 256, 0, stream>>>(src, dst, ew, deg, h, agg, E);

    // layer 2 (h2 overwrites h; agg2 overwrites agg after gemm2 is done)
    gemm2_kernel<<<rowBlocks, 256, 0, stream>>>(agg, b1, W2, h, N);
    selfloop_kernel<<<rowBlocks, 256, 0, stream>>>(h, deg, agg, N);
    edge_kernel<<<edgeBlocks, 256, 0, stream>>>(src, dst, ew, deg, h, agg, E);

    // pooling over sorted batch ids
    const int POOL_WAVES = 1024;
    int chunk = (N + POOL_WAVES - 1) / POOL_WAVES;
    pool_kernel<<<POOL_WAVES / 4, 256, 0, stream>>>(agg, bat, pooled, cnt, N, chunk);

    // final FC
    final_kernel<<<(NGRAPH * OUT_DIM + 255) / 256, 256, 0, stream>>>(pooled, cnt, b2, Wfc, bfc, out);
}

// Round 2
// 1029.192 us; speedup vs baseline: 1.8360x; 1.8360x over previous
//
#include <hip/hip_runtime.h>

#define IN_DIM 128
#define HID 64
#define OUT_DIM 128
#define NGRAPH 8

// ---------------- fused histogram + weighted degree ----------------
__global__ void histdeg_kernel(const int* __restrict__ dst, const float* __restrict__ ew,
                               int* __restrict__ count, float* __restrict__ deg, int E) {
    int i = blockIdx.x * blockDim.x + threadIdx.x;
    if (i < E) {
        int d = dst[i];
        atomicAdd(&count[d], 1);
        atomicAdd(&deg[d], ew[i]);
    }
}

// deg -> dinv = rsqrt(deg + 1)   (self-loop weight 1 always present => deg+1 > 0)
__global__ void dinv_kernel(float* __restrict__ deg, int N) {
    int i = blockIdx.x * blockDim.x + threadIdx.x;
    if (i < N) deg[i] = rsqrtf(deg[i] + 1.0f);
}

// ---------------- 2-level exclusive scan of count -> row_ptr ----------------
__global__ void scan_a(const int* __restrict__ count, int* __restrict__ row_ptr,
                       int* __restrict__ blocksums, int N) {
    __shared__ int sm[256];
    int i = blockIdx.x * 256 + threadIdx.x;
    int v = (i < N) ? count[i] : 0;
    sm[threadIdx.x] = v;
    __syncthreads();
    for (int off = 1; off < 256; off <<= 1) {
        int t = (threadIdx.x >= off) ? sm[threadIdx.x - off] : 0;
        __syncthreads();
        sm[threadIdx.x] += t;
        __syncthreads();
    }
    if (i < N) row_ptr[i] = sm[threadIdx.x] - v;   // exclusive within block
    if (threadIdx.x == 255) blocksums[blockIdx.x] = sm[255];
}

__global__ void scan_b(int* __restrict__ blocksums, int NB) {
    __shared__ int sm[512];
    int v = (threadIdx.x < NB) ? blocksums[threadIdx.x] : 0;
    sm[threadIdx.x] = v;
    __syncthreads();
    for (int off = 1; off < 512; off <<= 1) {
        int t = (threadIdx.x >= off) ? sm[threadIdx.x - off] : 0;
        __syncthreads();
        sm[threadIdx.x] += t;
        __syncthreads();
    }
    if (threadIdx.x < NB) blocksums[threadIdx.x] = sm[threadIdx.x] - v;  // exclusive
}

// row_ptr += block offset; cursor (= count array, reused) = row_ptr
__global__ void scan_c(int* __restrict__ row_ptr, const int* __restrict__ blocksums,
                       int* __restrict__ cursor, int N) {
    int i = blockIdx.x * blockDim.x + threadIdx.x;
    if (i < N) {
        int r = row_ptr[i] + blocksums[i >> 8];
        row_ptr[i] = r;
        cursor[i] = r;
    }
}

// ---------------- CSR fill: edges[pos] = {src, dinv[src]*ew} grouped by dst --
__global__ void fill_kernel(const int* __restrict__ src, const int* __restrict__ dst,
                            const float* __restrict__ ew, const float* __restrict__ dinv,
                            int* __restrict__ cursor, int2* __restrict__ edges, int E) {
    int e = blockIdx.x * blockDim.x + threadIdx.x;
    if (e >= E) return;
    int s = src[e], d = dst[e];
    int pos = atomicAdd(&cursor[d], 1);
    float coef = dinv[s] * ew[e];
    edges[pos] = make_int2(s, __float_as_int(coef));
}

// ---------------- layer 1 GEMM: h = x @ W1 ----------------------------------
// one wave per row, lane = output col (HID = 64)
__global__ void gemm1_kernel(const float* __restrict__ x, const float* __restrict__ W1,
                             float* __restrict__ h, int N) {
    int gid = blockIdx.x * blockDim.x + threadIdx.x;
    int row = gid >> 6, lane = gid & 63;
    if (row >= N) return;
    const float4* xr = reinterpret_cast<const float4*>(x + (size_t)row * IN_DIM);
    float acc = 0.f;
#pragma unroll
    for (int k4 = 0; k4 < IN_DIM / 4; ++k4) {
        float4 xv = xr[k4];
        int k = k4 * 4;
        acc += xv.x * W1[(k + 0) * HID + lane];
        acc += xv.y * W1[(k + 1) * HID + lane];
        acc += xv.z * W1[(k + 2) * HID + lane];
        acc += xv.w * W1[(k + 3) * HID + lane];
    }
    h[(size_t)row * HID + lane] = acc;
}

// ---------------- aggregation (gather form, no atomics) ----------------------
// out[d] = dinv[d] * ( sum_e coef_e * h[src_e] + dinv[d]*h[d] )
__global__ void agg_kernel(const int* __restrict__ row_ptr, const int* __restrict__ row_end,
                           const int2* __restrict__ edges, const float* __restrict__ dinv,
                           const float* __restrict__ h, float* __restrict__ agg, int N) {
    int gid = blockIdx.x * blockDim.x + threadIdx.x;
    int node = gid >> 6, lane = gid & 63;
    if (node >= N) return;
    int beg = row_ptr[node], end = row_end[node];
    float di = dinv[node];
    float acc = di * h[(size_t)node * HID + lane];   // self-loop (second di applied at end)
    int i = beg;
    for (; i + 4 <= end; i += 4) {
        int2 e0 = edges[i], e1 = edges[i + 1], e2 = edges[i + 2], e3 = edges[i + 3];
        float v0 = h[(size_t)e0.x * HID + lane];
        float v1 = h[(size_t)e1.x * HID + lane];
        float v2 = h[(size_t)e2.x * HID + lane];
        float v3 = h[(size_t)e3.x * HID + lane];
        acc += __int_as_float(e0.y) * v0;
        acc += __int_as_float(e1.y) * v1;
        acc += __int_as_float(e2.y) * v2;
        acc += __int_as_float(e3.y) * v3;
    }
    for (; i < end; ++i) {
        int2 e0 = edges[i];
        acc += __int_as_float(e0.y) * h[(size_t)e0.x * HID + lane];
    }
    agg[(size_t)node * HID + lane] = di * acc;
}

// ---------------- layer 2 GEMM: h2 = relu(agg1 + b1) @ W2 --------------------
__global__ void gemm2_kernel(const float* __restrict__ agg1, const float* __restrict__ b1,
                             const float* __restrict__ W2, float* __restrict__ h2, int N) {
    int gid = blockIdx.x * blockDim.x + threadIdx.x;
    int row = gid >> 6, lane = gid & 63;
    if (row >= N) return;
    const float4* ar = reinterpret_cast<const float4*>(agg1 + (size_t)row * HID);
    const float4* bv4 = reinterpret_cast<const float4*>(b1);
    float acc = 0.f;
#pragma unroll
    for (int k4 = 0; k4 < HID / 4; ++k4) {
        float4 av = ar[k4];
        float4 bv = bv4[k4];
        int k = k4 * 4;
        float a0 = fmaxf(av.x + bv.x, 0.f);
        float a1 = fmaxf(av.y + bv.y, 0.f);
        float a2 = fmaxf(av.z + bv.z, 0.f);
        float a3 = fmaxf(av.w + bv.w, 0.f);
        acc += a0 * W2[(k + 0) * HID + lane];
        acc += a1 * W2[(k + 1) * HID + lane];
        acc += a2 * W2[(k + 2) * HID + lane];
        acc += a3 * W2[(k + 3) * HID + lane];
    }
    h2[(size_t)row * HID + lane] = acc;
}

// ---------------- pooling: segment sum over sorted batch ---------------------
__global__ void pool_kernel(const float* __restrict__ agg2, const int* __restrict__ batch,
                            float* __restrict__ pooled, float* __restrict__ cnt,
                            int N, int chunk) {
    int wid = (blockIdx.x * blockDim.x + threadIdx.x) >> 6;
    int lane = threadIdx.x & 63;
    int start = wid * chunk;
    if (start >= N) return;
    int end = min(start + chunk, N);
    float acc = 0.f, fc = 0.f;
    int cur = batch[start];
    for (int n = start; n < end; ++n) {
        int g = batch[n];
        if (g != cur) {
            atomicAdd(&pooled[cur * HID + lane], acc);
            if (lane == 0) atomicAdd(&cnt[cur], fc);
            cur = g; acc = 0.f; fc = 0.f;
        }
        acc += agg2[(size_t)n * HID + lane];
        fc += 1.f;
    }
    atomicAdd(&pooled[cur * HID + lane], acc);
    if (lane == 0) atomicAdd(&cnt[cur], fc);
}

// ---------------- final: out = (pooled/cnt + b2) @ Wfc + bfc -----------------
__global__ void final_kernel(const float* __restrict__ pooled, const float* __restrict__ cnt,
                             const float* __restrict__ b2, const float* __restrict__ Wfc,
                             const float* __restrict__ bfc, float* __restrict__ out) {
    int idx = blockIdx.x * blockDim.x + threadIdx.x;
    if (idx >= NGRAPH * OUT_DIM) return;
    int g = idx >> 7, o = idx & 127;
    float inv = 1.0f / fmaxf(cnt[g], 1.0f);
    float acc = 0.f;
#pragma unroll
    for (int k = 0; k < HID; ++k)
        acc += (pooled[g * HID + k] * inv + b2[k]) * Wfc[k * OUT_DIM + o];
    out[idx] = acc + bfc[o];
}

extern "C" void kernel_launch(void* const* d_in, const int* in_sizes, int n_in,
                              void* d_out, int out_size, void* d_ws, size_t ws_size,
                              hipStream_t stream) {
    const float* x    = (const float*)d_in[0];
    const int*   ei   = (const int*)d_in[1];
    const float* ew   = (const float*)d_in[2];
    const int*   bat  = (const int*)d_in[3];
    const float* W1   = (const float*)d_in[4];
    const float* b1   = (const float*)d_in[5];
    const float* W2   = (const float*)d_in[6];
    const float* b2   = (const float*)d_in[7];
    const float* Wfc  = (const float*)d_in[8];
    const float* bfc  = (const float*)d_in[9];
    float* out = (float*)d_out;

    const int N = in_sizes[0] / IN_DIM;
    const int E = in_sizes[2];
    const int* src = ei;
    const int* dst = ei + E;

    // workspace layout (256B aligned regions)
    char* ws = (char*)d_ws;
    size_t off = 0;
    auto alloc = [&](size_t bytes) {
        char* p = ws + off;
        off += (bytes + 255) / 256 * 256;
        return p;
    };
    float* deg      = (float*)alloc((size_t)N * 4);          // becomes dinv
    int*   count    = (int*)  alloc((size_t)N * 4);          // histogram -> cursor -> row_end
    int*   row_ptr  = (int*)  alloc((size_t)N * 4);
    int*   blocksums= (int*)  alloc(512 * 4);
    float* pooled   = (float*)alloc((NGRAPH * HID + NGRAPH) * 4);
    float* cnt      = pooled + NGRAPH * HID;
    int2*  edges    = (int2*) alloc((size_t)E * 8);
    float* h        = (float*)alloc((size_t)N * HID * 4);
    float* agg      = (float*)alloc((size_t)N * HID * 4);

    hipMemsetAsync(deg, 0, (size_t)N * 4, stream);
    hipMemsetAsync(count, 0, (size_t)N * 4, stream);
    hipMemsetAsync(pooled, 0, (NGRAPH * HID + NGRAPH) * 4, stream);

    // degree + histogram + normalization
    histdeg_kernel<<<(E + 255) / 256, 256, 0, stream>>>(dst, ew, count, deg, E);
    dinv_kernel<<<(N + 255) / 256, 256, 0, stream>>>(deg, N);

    // CSR build (shared by both layers)
    int NB = (N + 255) / 256;
    scan_a<<<NB, 256, 0, stream>>>(count, row_ptr, blocksums, N);
    scan_b<<<1, 512, 0, stream>>>(blocksums, NB);
    scan_c<<<NB, 256, 0, stream>>>(row_ptr, blocksums, count, N);   // count becomes cursor
    fill_kernel<<<(E + 255) / 256, 256, 0, stream>>>(src, dst, ew, deg, count, edges, E);
    // after fill, count[d] == row_ptr[d] + degree(d)  (row_end)

    int rowBlocks = (int)(((size_t)N * 64 + 255) / 256);

    // layer 1
    gemm1_kernel<<<rowBlocks, 256, 0, stream>>>(x, W1, h, N);
    agg_kernel<<<rowBlocks, 256, 0, stream>>>(row_ptr, count, edges, deg, h, agg, N);

    // layer 2 (h2 overwrites h)
    gemm2_kernel<<<rowBlocks, 256, 0, stream>>>(agg, b1, W2, h, N);
    agg_kernel<<<rowBlocks, 256, 0, stream>>>(row_ptr, count, edges, deg, h, agg, N);

    // pooling over sorted batch ids
    const int POOL_WAVES = 1024;
    int chunk = (N + POOL_WAVES - 1) / POOL_WAVES;
    pool_kernel<<<POOL_WAVES / 4, 256, 0, stream>>>(agg, bat, pooled, cnt, N, chunk);

    // final FC
    final_kernel<<<(NGRAPH * OUT_DIM + 255) / 256, 256, 0, stream>>>(pooled, cnt, b2, Wfc, bfc, out);
}

// Round 3
// 826.904 us; speedup vs baseline: 2.2851x; 1.2446x over previous
//
#include <hip/hip_runtime.h>

#define IN_DIM 128
#define HID 64
#define OUT_DIM 128
#define NGRAPH 8

typedef unsigned long long u64;
typedef unsigned int u32;

// pack two f32 -> two bf16 (round-to-nearest-ish) in one u32: low=a, high=b
__device__ inline u32 pack_bf16(float a, float b) {
    u32 ua = (__float_as_uint(a) + 0x8000u) >> 16;
    u32 ub = (__float_as_uint(b) + 0x8000u) & 0xFFFF0000u;
    return ua | ub;
}
__device__ inline float bf16_lo(u32 v) { return __uint_as_float(v << 16); }
__device__ inline float bf16_hi(u32 v) { return __uint_as_float(v & 0xFFFF0000u); }

// ---- fused histogram + weighted degree via ONE packed 64-bit atomic --------
// bits 40..63: count ; bits 0..39: fixed-point (2^-32) sum of edge weights
// returned old value gives each edge its rank within its dst segment.
__global__ void histdeg_kernel(const int* __restrict__ dst, const float* __restrict__ ew,
                               u64* __restrict__ packed, int* __restrict__ rank, int E) {
    int i = blockIdx.x * blockDim.x + threadIdx.x;
    if (i >= E) return;
    int d = dst[i];
    u64 add = (1ull << 40) | (u64)(ew[i] * 4294967296.0f);
    u64 old = atomicAdd(&packed[d], add);
    rank[i] = (int)(old >> 40);
}

// packed -> dinv = rsqrt(deg+1), count
__global__ void unpack_kernel(const u64* __restrict__ packed, float* __restrict__ dinv,
                              int* __restrict__ count, int N) {
    int i = blockIdx.x * blockDim.x + threadIdx.x;
    if (i >= N) return;
    u64 p = packed[i];
    int c = (int)(p >> 40);
    float deg = (float)(p & 0xFFFFFFFFFFull) * (1.0f / 4294967296.0f);
    count[i] = c;
    dinv[i] = rsqrtf(deg + 1.0f);
}

// ---------------- 2-level exclusive scan of count -> row_ptr ----------------
__global__ void scan_a(const int* __restrict__ count, int* __restrict__ row_ptr,
                       int* __restrict__ blocksums, int N) {
    __shared__ int sm[256];
    int i = blockIdx.x * 256 + threadIdx.x;
    int v = (i < N) ? count[i] : 0;
    sm[threadIdx.x] = v;
    __syncthreads();
    for (int off = 1; off < 256; off <<= 1) {
        int t = (threadIdx.x >= off) ? sm[threadIdx.x - off] : 0;
        __syncthreads();
        sm[threadIdx.x] += t;
        __syncthreads();
    }
    if (i < N) row_ptr[i] = sm[threadIdx.x] - v;   // exclusive within block
    if (threadIdx.x == 255) blocksums[blockIdx.x] = sm[255];
}

__global__ void scan_b(int* __restrict__ blocksums, int NB) {
    __shared__ int sm[512];
    int v = (threadIdx.x < NB) ? blocksums[threadIdx.x] : 0;
    sm[threadIdx.x] = v;
    __syncthreads();
    for (int off = 1; off < 512; off <<= 1) {
        int t = (threadIdx.x >= off) ? sm[threadIdx.x - off] : 0;
        __syncthreads();
        sm[threadIdx.x] += t;
        __syncthreads();
    }
    if (threadIdx.x < NB) blocksums[threadIdx.x] = sm[threadIdx.x] - v;  // exclusive
}

// finalize row_ptr, compute row_end
__global__ void scan_c(int* __restrict__ row_ptr, const int* __restrict__ blocksums,
                       const int* __restrict__ count, int* __restrict__ row_end, int N) {
    int i = blockIdx.x * blockDim.x + threadIdx.x;
    if (i < N) {
        int r = row_ptr[i] + blocksums[i >> 8];
        row_ptr[i] = r;
        row_end[i] = r + count[i];
    }
}

// ---- CSR fill (NO atomics): pos = row_ptr[dst] + rank[e] -------------------
__global__ void fill_kernel(const int* __restrict__ src, const int* __restrict__ dst,
                            const float* __restrict__ ew, const float* __restrict__ dinv,
                            const int* __restrict__ row_ptr, const int* __restrict__ rank,
                            int2* __restrict__ edges, int E) {
    int e = blockIdx.x * blockDim.x + threadIdx.x;
    if (e >= E) return;
    int s = src[e], d = dst[e];
    int pos = row_ptr[d] + rank[e];
    float coef = dinv[s] * ew[e];
    edges[pos] = make_int2(s, __float_as_int(coef));
}

// ---------------- layer 1 GEMM: h = x @ W1, stored packed bf16 --------------
// one wave per row, lane = output col (HID = 64); pack pairs via shfl
__global__ void gemm1_kernel(const float* __restrict__ x, const float* __restrict__ W1,
                             u32* __restrict__ hb, int N) {
    int gid = blockIdx.x * blockDim.x + threadIdx.x;
    int row = gid >> 6, lane = gid & 63;
    if (row >= N) return;
    const float4* xr = reinterpret_cast<const float4*>(x + (size_t)row * IN_DIM);
    float acc = 0.f;
#pragma unroll
    for (int k4 = 0; k4 < IN_DIM / 4; ++k4) {
        float4 xv = xr[k4];
        int k = k4 * 4;
        acc += xv.x * W1[(k + 0) * HID + lane];
        acc += xv.y * W1[(k + 1) * HID + lane];
        acc += xv.z * W1[(k + 2) * HID + lane];
        acc += xv.w * W1[(k + 3) * HID + lane];
    }
    int l = lane & 31;
    float a0 = __shfl(acc, l * 2);
    float a1 = __shfl(acc, l * 2 + 1);
    if (lane < 32) hb[(size_t)row * 32 + l] = pack_bf16(a0, a1);
}

// ---- aggregation (gather, bf16 h, 2 edges per wave-iteration) --------------
// out[d] = dinv[d] * ( sum_e coef_e * h[src_e] + dinv[d]*h[d] )
__global__ void agg_kernel(const int* __restrict__ row_ptr, const int* __restrict__ row_end,
                           const int2* __restrict__ edges, const float* __restrict__ dinv,
                           const u32* __restrict__ hb, float* __restrict__ agg, int N) {
    int gid = blockIdx.x * blockDim.x + threadIdx.x;
    int node = gid >> 6, lane = gid & 63;
    if (node >= N) return;
    int half = lane >> 5, l = lane & 31;
    int beg = row_ptr[node], end = row_end[node];
    float di = dinv[node];
    float ax = 0.f, ay = 0.f;
    if (half == 0) {                        // self-loop term in half 0
        u32 hv = hb[(size_t)node * 32 + l];
        ax = di * bf16_lo(hv);
        ay = di * bf16_hi(hv);
    }
    for (int i = beg + half; i < end; i += 2) {
        int2 em = edges[i];                 // uniform within half-wave (L1 broadcast)
        float c = __int_as_float(em.y);
        u32 hv = hb[(size_t)em.x * 32 + l]; // 32 lanes x 4B = 128B coalesced
        ax += c * bf16_lo(hv);
        ay += c * bf16_hi(hv);
    }
    ax += __shfl_xor(ax, 32);
    ay += __shfl_xor(ay, 32);
    if (lane < 32)
        reinterpret_cast<float2*>(agg)[(size_t)node * 32 + l] = make_float2(di * ax, di * ay);
}

// ---------------- layer 2 GEMM: h2 = relu(agg1 + b1) @ W2 (bf16 out) --------
__global__ void gemm2_kernel(const float* __restrict__ agg1, const float* __restrict__ b1,
                             const float* __restrict__ W2, u32* __restrict__ hb, int N) {
    int gid = blockIdx.x * blockDim.x + threadIdx.x;
    int row = gid >> 6, lane = gid & 63;
    if (row >= N) return;
    const float4* ar = reinterpret_cast<const float4*>(agg1 + (size_t)row * HID);
    const float4* bv4 = reinterpret_cast<const float4*>(b1);
    float acc = 0.f;
#pragma unroll
    for (int k4 = 0; k4 < HID / 4; ++k4) {
        float4 av = ar[k4];
        float4 bv = bv4[k4];
        int k = k4 * 4;
        float a0 = fmaxf(av.x + bv.x, 0.f);
        float a1 = fmaxf(av.y + bv.y, 0.f);
        float a2 = fmaxf(av.z + bv.z, 0.f);
        float a3 = fmaxf(av.w + bv.w, 0.f);
        acc += a0 * W2[(k + 0) * HID + lane];
        acc += a1 * W2[(k + 1) * HID + lane];
        acc += a2 * W2[(k + 2) * HID + lane];
        acc += a3 * W2[(k + 3) * HID + lane];
    }
    int l = lane & 31;
    float p0 = __shfl(acc, l * 2);
    float p1 = __shfl(acc, l * 2 + 1);
    if (lane < 32) hb[(size_t)row * 32 + l] = pack_bf16(p0, p1);
}

// ---------------- pooling: segment sum over sorted batch ---------------------
__global__ void pool_kernel(const float* __restrict__ agg2, const int* __restrict__ batch,
                            float* __restrict__ pooled, float* __restrict__ cnt,
                            int N, int chunk) {
    int wid = (blockIdx.x * blockDim.x + threadIdx.x) >> 6;
    int lane = threadIdx.x & 63;
    int start = wid * chunk;
    if (start >= N) return;
    int end = min(start + chunk, N);
    float acc = 0.f, fc = 0.f;
    int cur = batch[start];
    for (int n = start; n < end; ++n) {
        int g = batch[n];
        if (g != cur) {
            atomicAdd(&pooled[cur * HID + lane], acc);
            if (lane == 0) atomicAdd(&cnt[cur], fc);
            cur = g; acc = 0.f; fc = 0.f;
        }
        acc += agg2[(size_t)n * HID + lane];
        fc += 1.f;
    }
    atomicAdd(&pooled[cur * HID + lane], acc);
    if (lane == 0) atomicAdd(&cnt[cur], fc);
}

// ---------------- final: out = (pooled/cnt + b2) @ Wfc + bfc -----------------
__global__ void final_kernel(const float* __restrict__ pooled, const float* __restrict__ cnt,
                             const float* __restrict__ b2, const float* __restrict__ Wfc,
                             const float* __restrict__ bfc, float* __restrict__ out) {
    int idx = blockIdx.x * blockDim.x + threadIdx.x;
    if (idx >= NGRAPH * OUT_DIM) return;
    int g = idx >> 7, o = idx & 127;
    float inv = 1.0f / fmaxf(cnt[g], 1.0f);
    float acc = 0.f;
#pragma unroll
    for (int k = 0; k < HID; ++k)
        acc += (pooled[g * HID + k] * inv + b2[k]) * Wfc[k * OUT_DIM + o];
    out[idx] = acc + bfc[o];
}

extern "C" void kernel_launch(void* const* d_in, const int* in_sizes, int n_in,
                              void* d_out, int out_size, void* d_ws, size_t ws_size,
                              hipStream_t stream) {
    const float* x    = (const float*)d_in[0];
    const int*   ei   = (const int*)d_in[1];
    const float* ew   = (const float*)d_in[2];
    const int*   bat  = (const int*)d_in[3];
    const float* W1   = (const float*)d_in[4];
    const float* b1   = (const float*)d_in[5];
    const float* W2   = (const float*)d_in[6];
    const float* b2   = (const float*)d_in[7];
    const float* Wfc  = (const float*)d_in[8];
    const float* bfc  = (const float*)d_in[9];
    float* out = (float*)d_out;

    const int N = in_sizes[0] / IN_DIM;
    const int E = in_sizes[2];
    const int* src = ei;
    const int* dst = ei + E;

    // workspace layout (256B aligned regions)
    char* ws = (char*)d_ws;
    size_t off = 0;
    auto alloc = [&](size_t bytes) {
        char* p = ws + off;
        off += (bytes + 255) / 256 * 256;
        return p;
    };
    u64*   packed   = (u64*)  alloc((size_t)N * 8);
    float* dinv     = (float*)alloc((size_t)N * 4);
    int*   count    = (int*)  alloc((size_t)N * 4);
    int*   row_ptr  = (int*)  alloc((size_t)N * 4);
    int*   row_end  = (int*)  alloc((size_t)N * 4);
    int*   blocksums= (int*)  alloc(512 * 4);
    float* pooled   = (float*)alloc((NGRAPH * HID + NGRAPH) * 4);
    float* cnt      = pooled + NGRAPH * HID;
    int*   rank     = (int*)  alloc((size_t)E * 4);
    int2*  edges    = (int2*) alloc((size_t)E * 8);
    u32*   hb       = (u32*)  alloc((size_t)N * 32 * 4);   // bf16-packed h
    float* agg      = (float*)alloc((size_t)N * HID * 4);

    hipMemsetAsync(packed, 0, (size_t)N * 8, stream);
    hipMemsetAsync(pooled, 0, (NGRAPH * HID + NGRAPH) * 4, stream);

    // histogram + weighted degree (one packed atomic) + per-edge rank
    histdeg_kernel<<<(E + 255) / 256, 256, 0, stream>>>(dst, ew, packed, rank, E);
    unpack_kernel<<<(N + 255) / 256, 256, 0, stream>>>(packed, dinv, count, N);

    // CSR build (shared by both layers), no cursor atomics
    int NB = (N + 255) / 256;
    scan_a<<<NB, 256, 0, stream>>>(count, row_ptr, blocksums, N);
    scan_b<<<1, 512, 0, stream>>>(blocksums, NB);
    scan_c<<<NB, 256, 0, stream>>>(row_ptr, blocksums, count, row_end, N);
    fill_kernel<<<(E + 255) / 256, 256, 0, stream>>>(src, dst, ew, dinv, row_ptr, rank, edges, E);

    int rowBlocks = (int)(((size_t)N * 64 + 255) / 256);

    // layer 1
    gemm1_kernel<<<rowBlocks, 256, 0, stream>>>(x, W1, hb, N);
    agg_kernel<<<rowBlocks, 256, 0, stream>>>(row_ptr, row_end, edges, dinv, hb, agg, N);

    // layer 2 (hb overwritten by gemm2)
    gemm2_kernel<<<rowBlocks, 256, 0, stream>>>(agg, b1, W2, hb, N);
    agg_kernel<<<rowBlocks, 256, 0, stream>>>(row_ptr, row_end, edges, dinv, hb, agg, N);

    // pooling over sorted batch ids
    const int POOL_WAVES = 1024;
    int chunk = (N + POOL_WAVES - 1) / POOL_WAVES;
    pool_kernel<<<POOL_WAVES / 4, 256, 0, stream>>>(agg, bat, pooled, cnt, N, chunk);

    // final FC
    final_kernel<<<(NGRAPH * OUT_DIM + 255) / 256, 256, 0, stream>>>(pooled, cnt, b2, Wfc, bfc, out);
}

// Round 4
// 583.421 us; speedup vs baseline: 3.2387x; 1.4173x over previous
//
#include <hip/hip_runtime.h>

#define IN_DIM 128
#define HID 64
#define OUT_DIM 128
#define NGRAPH 8

typedef unsigned long long u64;
typedef unsigned int u32;
typedef __attribute__((ext_vector_type(8))) short short8;   // 8 bf16
typedef __attribute__((ext_vector_type(4))) float f32x4;

__device__ inline short bf16b(float f) {                    // f32 -> bf16 bits (RNE)
    u32 u = __float_as_uint(f);
    return (short)((u + 0x7FFFu + ((u >> 16) & 1u)) >> 16);
}
// pack two f32 -> two bf16 in one u32: low = a, high = b
__device__ inline u32 pack_bf16(float a, float b) {
    u32 ua = (__float_as_uint(a) + 0x8000u) >> 16;
    u32 ub = (__float_as_uint(b) + 0x8000u) & 0xFFFF0000u;
    return ua | ub;
}
__device__ inline float bf16_lo(u32 v) { return __uint_as_float(v << 16); }
__device__ inline float bf16_hi(u32 v) { return __uint_as_float(v & 0xFFFF0000u); }

// ---- fused histogram + weighted degree via ONE packed 64-bit atomic --------
// bits 40..63: count ; bits 0..39: fixed-point (2^-32) sum of edge weights
__global__ void histdeg_kernel(const int* __restrict__ dst, const float* __restrict__ ew,
                               u64* __restrict__ packed, int* __restrict__ rank, int E) {
    int i = blockIdx.x * blockDim.x + threadIdx.x;
    if (i >= E) return;
    int d = dst[i];
    u64 add = (1ull << 40) | (u64)(ew[i] * 4294967296.0f);
    u64 old = atomicAdd(&packed[d], add);
    rank[i] = (int)(old >> 40);
}

__global__ void unpack_kernel(const u64* __restrict__ packed, float* __restrict__ dinv,
                              int* __restrict__ count, int N) {
    int i = blockIdx.x * blockDim.x + threadIdx.x;
    if (i >= N) return;
    u64 p = packed[i];
    int c = (int)(p >> 40);
    float deg = (float)(p & 0xFFFFFFFFFFull) * (1.0f / 4294967296.0f);
    count[i] = c;
    dinv[i] = rsqrtf(deg + 1.0f);
}

// ---------------- 2-level exclusive scan of count -> row_ptr ----------------
__global__ void scan_a(const int* __restrict__ count, int* __restrict__ row_ptr,
                       int* __restrict__ blocksums, int N) {
    __shared__ int sm[256];
    int i = blockIdx.x * 256 + threadIdx.x;
    int v = (i < N) ? count[i] : 0;
    sm[threadIdx.x] = v;
    __syncthreads();
    for (int off = 1; off < 256; off <<= 1) {
        int t = (threadIdx.x >= off) ? sm[threadIdx.x - off] : 0;
        __syncthreads();
        sm[threadIdx.x] += t;
        __syncthreads();
    }
    if (i < N) row_ptr[i] = sm[threadIdx.x] - v;
    if (threadIdx.x == 255) blocksums[blockIdx.x] = sm[255];
}

__global__ void scan_b(int* __restrict__ blocksums, int NB) {
    __shared__ int sm[512];
    int v = (threadIdx.x < NB) ? blocksums[threadIdx.x] : 0;
    sm[threadIdx.x] = v;
    __syncthreads();
    for (int off = 1; off < 512; off <<= 1) {
        int t = (threadIdx.x >= off) ? sm[threadIdx.x - off] : 0;
        __syncthreads();
        sm[threadIdx.x] += t;
        __syncthreads();
    }
    if (threadIdx.x < NB) blocksums[threadIdx.x] = sm[threadIdx.x] - v;
}

__global__ void scan_c(int* __restrict__ row_ptr, const int* __restrict__ blocksums,
                       const int* __restrict__ count, int* __restrict__ row_end, int N) {
    int i = blockIdx.x * blockDim.x + threadIdx.x;
    if (i < N) {
        int r = row_ptr[i] + blocksums[i >> 8];
        row_ptr[i] = r;
        row_end[i] = r + count[i];
    }
}

// ---- CSR fill (NO atomics): pos = row_ptr[dst] + rank[e] -------------------
__global__ void fill_kernel(const int* __restrict__ src, const int* __restrict__ dst,
                            const float* __restrict__ ew, const float* __restrict__ dinv,
                            const int* __restrict__ row_ptr, const int* __restrict__ rank,
                            int2* __restrict__ edges, int E) {
    int e = blockIdx.x * blockDim.x + threadIdx.x;
    if (e >= E) return;
    int s = src[e], d = dst[e];
    int pos = row_ptr[d] + rank[e];
    float coef = dinv[s] * ew[e];
    edges[pos] = make_int2(s, __float_as_int(coef));
}

// ---------------- layer 1 GEMM via MFMA: h = x @ W1 (bf16-packed out) -------
// 64 rows/block, 4 waves; wave w owns rows w*16..w*16+15, all 64 cols.
// hb[row*32 + c] packs (feat c, feat c+32).
__global__ __launch_bounds__(256) void gemm1_kernel(const float* __restrict__ x,
                                                    const float* __restrict__ W1,
                                                    u32* __restrict__ hb, int N) {
    int wave = threadIdx.x >> 6, lane = threadIdx.x & 63;
    int col = lane & 15, kg = lane >> 4;
    int rowbase = blockIdx.x * 64 + wave * 16;

    // B fragments (all of W1) in registers: b[j] = W1[k0+j][nt*16+col], k0 = ks*32+kg*8
    short8 bW[4][4];
#pragma unroll
    for (int ks = 0; ks < 4; ++ks)
#pragma unroll
        for (int nt = 0; nt < 4; ++nt) {
            const float* wp = W1 + (size_t)(ks * 32 + kg * 8) * HID + nt * 16 + col;
            short8 f;
#pragma unroll
            for (int j = 0; j < 8; ++j) f[j] = bf16b(wp[j * HID]);
            bW[ks][nt] = f;
        }

    f32x4 acc[4];
#pragma unroll
    for (int nt = 0; nt < 4; ++nt) acc[nt] = (f32x4){0.f, 0.f, 0.f, 0.f};

    int arow = rowbase + col;
    if (arow >= N) arow = N - 1;
    const float4* xr = reinterpret_cast<const float4*>(x + (size_t)arow * IN_DIM);
#pragma unroll
    for (int ks = 0; ks < 4; ++ks) {
        float4 xa = xr[ks * 8 + kg * 2];
        float4 xb = xr[ks * 8 + kg * 2 + 1];
        short8 a;
        a[0] = bf16b(xa.x); a[1] = bf16b(xa.y); a[2] = bf16b(xa.z); a[3] = bf16b(xa.w);
        a[4] = bf16b(xb.x); a[5] = bf16b(xb.y); a[6] = bf16b(xb.z); a[7] = bf16b(xb.w);
#pragma unroll
        for (int nt = 0; nt < 4; ++nt)
            acc[nt] = __builtin_amdgcn_mfma_f32_16x16x32_bf16(a, bW[ks][nt], acc[nt], 0, 0, 0);
    }

    // D layout: row = kg*4 + r (local), col = nt*16 + (lane&15)
#pragma unroll
    for (int r = 0; r < 4; ++r) {
        int row = rowbase + kg * 4 + r;
        if (row < N) {
            hb[(size_t)row * 32 + col]      = pack_bf16(acc[0][r], acc[2][r]);
            hb[(size_t)row * 32 + col + 16] = pack_bf16(acc[1][r], acc[3][r]);
        }
    }
}

// ---- aggregation (gather, bf16 h, 2 edges per wave-iteration) --------------
// hb pair at lane l is (feat l, feat l+32); agg written in natural [N][64].
__global__ void agg_kernel(const int* __restrict__ row_ptr, const int* __restrict__ row_end,
                           const int2* __restrict__ edges, const float* __restrict__ dinv,
                           const u32* __restrict__ hb, float* __restrict__ agg, int N) {
    int gid = blockIdx.x * blockDim.x + threadIdx.x;
    int node = gid >> 6, lane = gid & 63;
    if (node >= N) return;
    int half = lane >> 5, l = lane & 31;
    int beg = row_ptr[node], end = row_end[node];
    float di = dinv[node];
    float ax = 0.f, ay = 0.f;
    if (half == 0) {
        u32 hv = hb[(size_t)node * 32 + l];
        ax = di * bf16_lo(hv);
        ay = di * bf16_hi(hv);
    }
    for (int i = beg + half; i < end; i += 2) {
        int2 em = edges[i];
        float c = __int_as_float(em.y);
        u32 hv = hb[(size_t)em.x * 32 + l];
        ax += c * bf16_lo(hv);
        ay += c * bf16_hi(hv);
    }
    ax += __shfl_xor(ax, 32);
    ay += __shfl_xor(ay, 32);
    if (lane < 32) {
        agg[(size_t)node * HID + l]      = di * ax;
        agg[(size_t)node * HID + 32 + l] = di * ay;
    }
}

// ---------------- layer 2 GEMM via MFMA: h2 = relu(agg1 + b1) @ W2 ----------
__global__ __launch_bounds__(256) void gemm2_kernel(const float* __restrict__ agg1,
                                                    const float* __restrict__ b1,
                                                    const float* __restrict__ W2,
                                                    u32* __restrict__ hb, int N) {
    int wave = threadIdx.x >> 6, lane = threadIdx.x & 63;
    int col = lane & 15, kg = lane >> 4;
    int rowbase = blockIdx.x * 64 + wave * 16;

    short8 bW[2][4];
#pragma unroll
    for (int ks = 0; ks < 2; ++ks)
#pragma unroll
        for (int nt = 0; nt < 4; ++nt) {
            const float* wp = W2 + (size_t)(ks * 32 + kg * 8) * HID + nt * 16 + col;
            short8 f;
#pragma unroll
            for (int j = 0; j < 8; ++j) f[j] = bf16b(wp[j * HID]);
            bW[ks][nt] = f;
        }

    const float4* bp = reinterpret_cast<const float4*>(b1);
    float4 bb0[2], bb1[2];
#pragma unroll
    for (int ks = 0; ks < 2; ++ks) {
        bb0[ks] = bp[ks * 8 + kg * 2];
        bb1[ks] = bp[ks * 8 + kg * 2 + 1];
    }

    f32x4 acc[4];
#pragma unroll
    for (int nt = 0; nt < 4; ++nt) acc[nt] = (f32x4){0.f, 0.f, 0.f, 0.f};

    int arow = rowbase + col;
    if (arow >= N) arow = N - 1;
    const float4* ar = reinterpret_cast<const float4*>(agg1 + (size_t)arow * HID);
#pragma unroll
    for (int ks = 0; ks < 2; ++ks) {
        float4 xa = ar[ks * 8 + kg * 2];
        float4 xb = ar[ks * 8 + kg * 2 + 1];
        short8 a;
        a[0] = bf16b(fmaxf(xa.x + bb0[ks].x, 0.f));
        a[1] = bf16b(fmaxf(xa.y + bb0[ks].y, 0.f));
        a[2] = bf16b(fmaxf(xa.z + bb0[ks].z, 0.f));
        a[3] = bf16b(fmaxf(xa.w + bb0[ks].w, 0.f));
        a[4] = bf16b(fmaxf(xb.x + bb1[ks].x, 0.f));
        a[5] = bf16b(fmaxf(xb.y + bb1[ks].y, 0.f));
        a[6] = bf16b(fmaxf(xb.z + bb1[ks].z, 0.f));
        a[7] = bf16b(fmaxf(xb.w + bb1[ks].w, 0.f));
#pragma unroll
        for (int nt = 0; nt < 4; ++nt)
            acc[nt] = __builtin_amdgcn_mfma_f32_16x16x32_bf16(a, bW[ks][nt], acc[nt], 0, 0, 0);
    }

#pragma unroll
    for (int r = 0; r < 4; ++r) {
        int row = rowbase + kg * 4 + r;
        if (row < N) {
            hb[(size_t)row * 32 + col]      = pack_bf16(acc[0][r], acc[2][r]);
            hb[(size_t)row * 32 + col + 16] = pack_bf16(acc[1][r], acc[3][r]);
        }
    }
}

// ---------------- pooling: segment sum over sorted batch ---------------------
__global__ void pool_kernel(const float* __restrict__ agg2, const int* __restrict__ batch,
                            float* __restrict__ pooled, float* __restrict__ cnt,
                            int N, int chunk) {
    int wid = (blockIdx.x * blockDim.x + threadIdx.x) >> 6;
    int lane = threadIdx.x & 63;
    int start = wid * chunk;
    if (start >= N) return;
    int end = min(start + chunk, N);
    float acc = 0.f, fc = 0.f;
    int cur = batch[start];
    for (int n = start; n < end; ++n) {
        int g = batch[n];
        if (g != cur) {
            atomicAdd(&pooled[cur * HID + lane], acc);
            if (lane == 0) atomicAdd(&cnt[cur], fc);
            cur = g; acc = 0.f; fc = 0.f;
        }
        acc += agg2[(size_t)n * HID + lane];
        fc += 1.f;
    }
    atomicAdd(&pooled[cur * HID + lane], acc);
    if (lane == 0) atomicAdd(&cnt[cur], fc);
}

// ---------------- final: out = (pooled/cnt + b2) @ Wfc + bfc -----------------
__global__ void final_kernel(const float* __restrict__ pooled, const float* __restrict__ cnt,
                             const float* __restrict__ b2, const float* __restrict__ Wfc,
                             const float* __restrict__ bfc, float* __restrict__ out) {
    int idx = blockIdx.x * blockDim.x + threadIdx.x;
    if (idx >= NGRAPH * OUT_DIM) return;
    int g = idx >> 7, o = idx & 127;
    float inv = 1.0f / fmaxf(cnt[g], 1.0f);
    float acc = 0.f;
#pragma unroll
    for (int k = 0; k < HID; ++k)
        acc += (pooled[g * HID + k] * inv + b2[k]) * Wfc[k * OUT_DIM + o];
    out[idx] = acc + bfc[o];
}

extern "C" void kernel_launch(void* const* d_in, const int* in_sizes, int n_in,
                              void* d_out, int out_size, void* d_ws, size_t ws_size,
                              hipStream_t stream) {
    const float* x    = (const float*)d_in[0];
    const int*   ei   = (const int*)d_in[1];
    const float* ew   = (const float*)d_in[2];
    const int*   bat  = (const int*)d_in[3];
    const float* W1   = (const float*)d_in[4];
    const float* b1   = (const float*)d_in[5];
    const float* W2   = (const float*)d_in[6];
    const float* b2   = (const float*)d_in[7];
    const float* Wfc  = (const float*)d_in[8];
    const float* bfc  = (const float*)d_in[9];
    float* out = (float*)d_out;

    const int N = in_sizes[0] / IN_DIM;
    const int E = in_sizes[2];
    const int* src = ei;
    const int* dst = ei + E;

    char* ws = (char*)d_ws;
    size_t off = 0;
    auto alloc = [&](size_t bytes) {
        char* p = ws + off;
        off += (bytes + 255) / 256 * 256;
        return p;
    };
    u64*   packed   = (u64*)  alloc((size_t)N * 8);
    float* dinv     = (float*)alloc((size_t)N * 4);
    int*   count    = (int*)  alloc((size_t)N * 4);
    int*   row_ptr  = (int*)  alloc((size_t)N * 4);
    int*   row_end  = (int*)  alloc((size_t)N * 4);
    int*   blocksums= (int*)  alloc(512 * 4);
    float* pooled   = (float*)alloc((NGRAPH * HID + NGRAPH) * 4);
    float* cnt      = pooled + NGRAPH * HID;
    int*   rank     = (int*)  alloc((size_t)E * 4);
    int2*  edges    = (int2*) alloc((size_t)E * 8);
    u32*   hb       = (u32*)  alloc((size_t)N * 32 * 4);   // bf16-packed h
    float* agg      = (float*)alloc((size_t)N * HID * 4);

    hipMemsetAsync(packed, 0, (size_t)N * 8, stream);
    hipMemsetAsync(pooled, 0, (NGRAPH * HID + NGRAPH) * 4, stream);

    histdeg_kernel<<<(E + 255) / 256, 256, 0, stream>>>(dst, ew, packed, rank, E);
    unpack_kernel<<<(N + 255) / 256, 256, 0, stream>>>(packed, dinv, count, N);

    int NB = (N + 255) / 256;
    scan_a<<<NB, 256, 0, stream>>>(count, row_ptr, blocksums, N);
    scan_b<<<1, 512, 0, stream>>>(blocksums, NB);
    scan_c<<<NB, 256, 0, stream>>>(row_ptr, blocksums, count, row_end, N);
    fill_kernel<<<(E + 255) / 256, 256, 0, stream>>>(src, dst, ew, dinv, row_ptr, rank, edges, E);

    int gemmBlocks = (N + 63) / 64;
    int rowBlocks = (int)(((size_t)N * 64 + 255) / 256);

    // layer 1
    gemm1_kernel<<<gemmBlocks, 256, 0, stream>>>(x, W1, hb, N);
    agg_kernel<<<rowBlocks, 256, 0, stream>>>(row_ptr, row_end, edges, dinv, hb, agg, N);

    // layer 2
    gemm2_kernel<<<gemmBlocks, 256, 0, stream>>>(agg, b1, W2, hb, N);
    agg_kernel<<<rowBlocks, 256, 0, stream>>>(row_ptr, row_end, edges, dinv, hb, agg, N);

    // pooling
    const int POOL_WAVES = 1024;
    int chunk = (N + POOL_WAVES - 1) / POOL_WAVES;
    pool_kernel<<<POOL_WAVES / 4, 256, 0, stream>>>(agg, bat, pooled, cnt, N, chunk);

    final_kernel<<<(NGRAPH * OUT_DIM + 255) / 256, 256, 0, stream>>>(pooled, cnt, b2, Wfc, bfc, out);
}

// Round 5
// 435.095 us; speedup vs baseline: 4.3429x; 1.3409x over previous
//
#include <hip/hip_runtime.h>

#define IN_DIM 128
#define HID 64
#define OUT_DIM 128
#define NGRAPH 8

typedef unsigned long long u64;
typedef unsigned int u32;
typedef __attribute__((ext_vector_type(8))) short short8;   // 8 bf16
typedef __attribute__((ext_vector_type(4))) float f32x4;

__device__ inline short bf16b(float f) {                    // f32 -> bf16 bits (RNE)
    u32 u = __float_as_uint(f);
    return (short)((u + 0x7FFFu + ((u >> 16) & 1u)) >> 16);
}
// pack two f32 -> two bf16 in one u32: low = a, high = b
__device__ inline u32 pack_bf16(float a, float b) {
    u32 ua = (__float_as_uint(a) + 0x8000u) >> 16;
    u32 ub = (__float_as_uint(b) + 0x8000u) & 0xFFFF0000u;
    return ua | ub;
}
__device__ inline float bf16_lo(u32 v) { return __uint_as_float(v << 16); }
__device__ inline float bf16_hi(u32 v) { return __uint_as_float(v & 0xFFFF0000u); }

// ---- fused histogram + weighted degree via ONE packed 64-bit atomic --------
// bits 40..63: count ; bits 0..39: fixed-point (2^-32) sum of edge weights
// 4 grid-strided edges per thread -> 4 atomics in flight (MLP).
__global__ void histdeg_kernel(const int* __restrict__ dst, const float* __restrict__ ew,
                               u64* __restrict__ packed, int* __restrict__ rank,
                               int E, int T) {
    int t = blockIdx.x * blockDim.x + threadIdx.x;
    if (t >= T) return;
    int i0 = t, i1 = t + T, i2 = t + 2 * T, i3 = t + 3 * T;
    bool v1 = i1 < E, v2 = i2 < E, v3 = i3 < E;
    int d0 = dst[i0];
    int d1 = v1 ? dst[i1] : 0;
    int d2 = v2 ? dst[i2] : 0;
    int d3 = v3 ? dst[i3] : 0;
    float w0 = ew[i0];
    float w1 = v1 ? ew[i1] : 0.f;
    float w2 = v2 ? ew[i2] : 0.f;
    float w3 = v3 ? ew[i3] : 0.f;
    u64 old0 = 0, old1 = 0, old2 = 0, old3 = 0;
    old0 = atomicAdd(&packed[d0], (1ull << 40) | (u64)(w0 * 4294967296.0f));
    if (v1) old1 = atomicAdd(&packed[d1], (1ull << 40) | (u64)(w1 * 4294967296.0f));
    if (v2) old2 = atomicAdd(&packed[d2], (1ull << 40) | (u64)(w2 * 4294967296.0f));
    if (v3) old3 = atomicAdd(&packed[d3], (1ull << 40) | (u64)(w3 * 4294967296.0f));
    rank[i0] = (int)(old0 >> 40);
    if (v1) rank[i1] = (int)(old1 >> 40);
    if (v2) rank[i2] = (int)(old2 >> 40);
    if (v3) rank[i3] = (int)(old3 >> 40);
}

__global__ void unpack_kernel(const u64* __restrict__ packed, float* __restrict__ dinv,
                              int* __restrict__ count, int N) {
    int i = blockIdx.x * blockDim.x + threadIdx.x;
    if (i >= N) return;
    u64 p = packed[i];
    int c = (int)(p >> 40);
    float deg = (float)(p & 0xFFFFFFFFFFull) * (1.0f / 4294967296.0f);
    count[i] = c;
    dinv[i] = rsqrtf(deg + 1.0f);
}

// ---------------- 2-level exclusive scan of count -> row_ptr ----------------
__global__ void scan_a(const int* __restrict__ count, int* __restrict__ row_ptr,
                       int* __restrict__ blocksums, int N) {
    __shared__ int sm[256];
    int i = blockIdx.x * 256 + threadIdx.x;
    int v = (i < N) ? count[i] : 0;
    sm[threadIdx.x] = v;
    __syncthreads();
    for (int off = 1; off < 256; off <<= 1) {
        int t = (threadIdx.x >= off) ? sm[threadIdx.x - off] : 0;
        __syncthreads();
        sm[threadIdx.x] += t;
        __syncthreads();
    }
    if (i < N) row_ptr[i] = sm[threadIdx.x] - v;
    if (threadIdx.x == 255) blocksums[blockIdx.x] = sm[255];
}

__global__ void scan_b(int* __restrict__ blocksums, int NB) {
    __shared__ int sm[512];
    int v = (threadIdx.x < NB) ? blocksums[threadIdx.x] : 0;
    sm[threadIdx.x] = v;
    __syncthreads();
    for (int off = 1; off < 512; off <<= 1) {
        int t = (threadIdx.x >= off) ? sm[threadIdx.x - off] : 0;
        __syncthreads();
        sm[threadIdx.x] += t;
        __syncthreads();
    }
    if (threadIdx.x < NB) blocksums[threadIdx.x] = sm[threadIdx.x] - v;
}

__global__ void scan_c(int* __restrict__ row_ptr, const int* __restrict__ blocksums,
                       const int* __restrict__ count, int* __restrict__ row_end, int N) {
    int i = blockIdx.x * blockDim.x + threadIdx.x;
    if (i < N) {
        int r = row_ptr[i] + blocksums[i >> 8];
        row_ptr[i] = r;
        row_end[i] = r + count[i];
    }
}

// ---- CSR fill (NO atomics): pos = row_ptr[dst] + rank[e] -------------------
__global__ void fill_kernel(const int* __restrict__ src, const int* __restrict__ dst,
                            const float* __restrict__ ew, const float* __restrict__ dinv,
                            const int* __restrict__ row_ptr, const int* __restrict__ rank,
                            int2* __restrict__ edges, int E) {
    int e = blockIdx.x * blockDim.x + threadIdx.x;
    if (e >= E) return;
    int s = src[e], d = dst[e];
    int pos = row_ptr[d] + rank[e];
    float coef = dinv[s] * ew[e];
    edges[pos] = make_int2(s, __float_as_int(coef));
}

// ---------------- layer 1 GEMM via MFMA: h = x @ W1 (bf16-packed out) -------
__global__ __launch_bounds__(256) void gemm1_kernel(const float* __restrict__ x,
                                                    const float* __restrict__ W1,
                                                    u32* __restrict__ hb, int N) {
    int wave = threadIdx.x >> 6, lane = threadIdx.x & 63;
    int col = lane & 15, kg = lane >> 4;
    int rowbase = blockIdx.x * 64 + wave * 16;

    short8 bW[4][4];
#pragma unroll
    for (int ks = 0; ks < 4; ++ks)
#pragma unroll
        for (int nt = 0; nt < 4; ++nt) {
            const float* wp = W1 + (size_t)(ks * 32 + kg * 8) * HID + nt * 16 + col;
            short8 f;
#pragma unroll
            for (int j = 0; j < 8; ++j) f[j] = bf16b(wp[j * HID]);
            bW[ks][nt] = f;
        }

    f32x4 acc[4];
#pragma unroll
    for (int nt = 0; nt < 4; ++nt) acc[nt] = (f32x4){0.f, 0.f, 0.f, 0.f};

    int arow = rowbase + col;
    if (arow >= N) arow = N - 1;
    const float4* xr = reinterpret_cast<const float4*>(x + (size_t)arow * IN_DIM);
#pragma unroll
    for (int ks = 0; ks < 4; ++ks) {
        float4 xa = xr[ks * 8 + kg * 2];
        float4 xb = xr[ks * 8 + kg * 2 + 1];
        short8 a;
        a[0] = bf16b(xa.x); a[1] = bf16b(xa.y); a[2] = bf16b(xa.z); a[3] = bf16b(xa.w);
        a[4] = bf16b(xb.x); a[5] = bf16b(xb.y); a[6] = bf16b(xb.z); a[7] = bf16b(xb.w);
#pragma unroll
        for (int nt = 0; nt < 4; ++nt)
            acc[nt] = __builtin_amdgcn_mfma_f32_16x16x32_bf16(a, bW[ks][nt], acc[nt], 0, 0, 0);
    }

#pragma unroll
    for (int r = 0; r < 4; ++r) {
        int row = rowbase + kg * 4 + r;
        if (row < N) {
            hb[(size_t)row * 32 + col]      = pack_bf16(acc[0][r], acc[2][r]);
            hb[(size_t)row * 32 + col + 16] = pack_bf16(acc[1][r], acc[3][r]);
        }
    }
}

// ---- aggregation (gather, bf16 h) ------------------------------------------
// Contiguous half-split of each node's range + 4x unroll -> 4 gathers in flight.
__global__ void agg_kernel(const int* __restrict__ row_ptr, const int* __restrict__ row_end,
                           const int2* __restrict__ edges, const float* __restrict__ dinv,
                           const u32* __restrict__ hb, float* __restrict__ agg, int N) {
    int gid = blockIdx.x * blockDim.x + threadIdx.x;
    int node = gid >> 6, lane = gid & 63;
    if (node >= N) return;
    int half = lane >> 5, l = lane & 31;
    int beg = row_ptr[node], end = row_end[node];
    int mid = beg + ((end - beg + 1) >> 1);
    int i0 = half ? mid : beg;
    int i1 = half ? end : mid;
    float di = dinv[node];
    float ax = 0.f, ay = 0.f;
    if (half == 0) {                        // self-loop term
        u32 hv = hb[(size_t)node * 32 + l];
        ax = di * bf16_lo(hv);
        ay = di * bf16_hi(hv);
    }
    int i = i0;
    for (; i + 4 <= i1; i += 4) {
        int2 e0 = edges[i], e1 = edges[i + 1], e2 = edges[i + 2], e3 = edges[i + 3];
        u32 h0 = hb[(size_t)e0.x * 32 + l];
        u32 h1 = hb[(size_t)e1.x * 32 + l];
        u32 h2 = hb[(size_t)e2.x * 32 + l];
        u32 h3 = hb[(size_t)e3.x * 32 + l];
        float c0 = __int_as_float(e0.y), c1 = __int_as_float(e1.y);
        float c2 = __int_as_float(e2.y), c3 = __int_as_float(e3.y);
        ax += c0 * bf16_lo(h0); ay += c0 * bf16_hi(h0);
        ax += c1 * bf16_lo(h1); ay += c1 * bf16_hi(h1);
        ax += c2 * bf16_lo(h2); ay += c2 * bf16_hi(h2);
        ax += c3 * bf16_lo(h3); ay += c3 * bf16_hi(h3);
    }
    for (; i < i1; ++i) {
        int2 em = edges[i];
        float c = __int_as_float(em.y);
        u32 hv = hb[(size_t)em.x * 32 + l];
        ax += c * bf16_lo(hv);
        ay += c * bf16_hi(hv);
    }
    ax += __shfl_xor(ax, 32);
    ay += __shfl_xor(ay, 32);
    if (lane < 32) {
        agg[(size_t)node * HID + l]      = di * ax;
        agg[(size_t)node * HID + 32 + l] = di * ay;
    }
}

// ---------------- layer 2 GEMM via MFMA: h2 = relu(agg1 + b1) @ W2 ----------
__global__ __launch_bounds__(256) void gemm2_kernel(const float* __restrict__ agg1,
                                                    const float* __restrict__ b1,
                                                    const float* __restrict__ W2,
                                                    u32* __restrict__ hb, int N) {
    int wave = threadIdx.x >> 6, lane = threadIdx.x & 63;
    int col = lane & 15, kg = lane >> 4;
    int rowbase = blockIdx.x * 64 + wave * 16;

    short8 bW[2][4];
#pragma unroll
    for (int ks = 0; ks < 2; ++ks)
#pragma unroll
        for (int nt = 0; nt < 4; ++nt) {
            const float* wp = W2 + (size_t)(ks * 32 + kg * 8) * HID + nt * 16 + col;
            short8 f;
#pragma unroll
            for (int j = 0; j < 8; ++j) f[j] = bf16b(wp[j * HID]);
            bW[ks][nt] = f;
        }

    const float4* bp = reinterpret_cast<const float4*>(b1);
    float4 bb0[2], bb1[2];
#pragma unroll
    for (int ks = 0; ks < 2; ++ks) {
        bb0[ks] = bp[ks * 8 + kg * 2];
        bb1[ks] = bp[ks * 8 + kg * 2 + 1];
    }

    f32x4 acc[4];
#pragma unroll
    for (int nt = 0; nt < 4; ++nt) acc[nt] = (f32x4){0.f, 0.f, 0.f, 0.f};

    int arow = rowbase + col;
    if (arow >= N) arow = N - 1;
    const float4* ar = reinterpret_cast<const float4*>(agg1 + (size_t)arow * HID);
#pragma unroll
    for (int ks = 0; ks < 2; ++ks) {
        float4 xa = ar[ks * 8 + kg * 2];
        float4 xb = ar[ks * 8 + kg * 2 + 1];
        short8 a;
        a[0] = bf16b(fmaxf(xa.x + bb0[ks].x, 0.f));
        a[1] = bf16b(fmaxf(xa.y + bb0[ks].y, 0.f));
        a[2] = bf16b(fmaxf(xa.z + bb0[ks].z, 0.f));
        a[3] = bf16b(fmaxf(xa.w + bb0[ks].w, 0.f));
        a[4] = bf16b(fmaxf(xb.x + bb1[ks].x, 0.f));
        a[5] = bf16b(fmaxf(xb.y + bb1[ks].y, 0.f));
        a[6] = bf16b(fmaxf(xb.z + bb1[ks].z, 0.f));
        a[7] = bf16b(fmaxf(xb.w + bb1[ks].w, 0.f));
#pragma unroll
        for (int nt = 0; nt < 4; ++nt)
            acc[nt] = __builtin_amdgcn_mfma_f32_16x16x32_bf16(a, bW[ks][nt], acc[nt], 0, 0, 0);
    }

#pragma unroll
    for (int r = 0; r < 4; ++r) {
        int row = rowbase + kg * 4 + r;
        if (row < N) {
            hb[(size_t)row * 32 + col]      = pack_bf16(acc[0][r], acc[2][r]);
            hb[(size_t)row * 32 + col + 16] = pack_bf16(acc[1][r], acc[3][r]);
        }
    }
}

// ---------------- pooling: segment sum over sorted batch ---------------------
__global__ void pool_kernel(const float* __restrict__ agg2, const int* __restrict__ batch,
                            float* __restrict__ pooled, float* __restrict__ cnt,
                            int N, int chunk) {
    int wid = (blockIdx.x * blockDim.x + threadIdx.x) >> 6;
    int lane = threadIdx.x & 63;
    int start = wid * chunk;
    if (start >= N) return;
    int end = min(start + chunk, N);
    float acc = 0.f, fc = 0.f;
    int cur = batch[start];
    for (int n = start; n < end; ++n) {
        int g = batch[n];
        if (g != cur) {
            atomicAdd(&pooled[cur * HID + lane], acc);
            if (lane == 0) atomicAdd(&cnt[cur], fc);
            cur = g; acc = 0.f; fc = 0.f;
        }
        acc += agg2[(size_t)n * HID + lane];
        fc += 1.f;
    }
    atomicAdd(&pooled[cur * HID + lane], acc);
    if (lane == 0) atomicAdd(&cnt[cur], fc);
}

// ---------------- final: out = (pooled/cnt + b2) @ Wfc + bfc -----------------
__global__ void final_kernel(const float* __restrict__ pooled, const float* __restrict__ cnt,
                             const float* __restrict__ b2, const float* __restrict__ Wfc,
                             const float* __restrict__ bfc, float* __restrict__ out) {
    int idx = blockIdx.x * blockDim.x + threadIdx.x;
    if (idx >= NGRAPH * OUT_DIM) return;
    int g = idx >> 7, o = idx & 127;
    float inv = 1.0f / fmaxf(cnt[g], 1.0f);
    float acc = 0.f;
#pragma unroll
    for (int k = 0; k < HID; ++k)
        acc += (pooled[g * HID + k] * inv + b2[k]) * Wfc[k * OUT_DIM + o];
    out[idx] = acc + bfc[o];
}

extern "C" void kernel_launch(void* const* d_in, const int* in_sizes, int n_in,
                              void* d_out, int out_size, void* d_ws, size_t ws_size,
                              hipStream_t stream) {
    const float* x    = (const float*)d_in[0];
    const int*   ei   = (const int*)d_in[1];
    const float* ew   = (const float*)d_in[2];
    const int*   bat  = (const int*)d_in[3];
    const float* W1   = (const float*)d_in[4];
    const float* b1   = (const float*)d_in[5];
    const float* W2   = (const float*)d_in[6];
    const float* b2   = (const float*)d_in[7];
    const float* Wfc  = (const float*)d_in[8];
    const float* bfc  = (const float*)d_in[9];
    float* out = (float*)d_out;

    const int N = in_sizes[0] / IN_DIM;
    const int E = in_sizes[2];
    const int* src = ei;
    const int* dst = ei + E;

    char* ws = (char*)d_ws;
    size_t off = 0;
    auto alloc = [&](size_t bytes) {
        char* p = ws + off;
        off += (bytes + 255) / 256 * 256;
        return p;
    };
    u64*   packed   = (u64*)  alloc((size_t)N * 8);
    float* dinv     = (float*)alloc((size_t)N * 4);
    int*   count    = (int*)  alloc((size_t)N * 4);
    int*   row_ptr  = (int*)  alloc((size_t)N * 4);
    int*   row_end  = (int*)  alloc((size_t)N * 4);
    int*   blocksums= (int*)  alloc(512 * 4);
    float* pooled   = (float*)alloc((NGRAPH * HID + NGRAPH) * 4);
    float* cnt      = pooled + NGRAPH * HID;
    int*   rank     = (int*)  alloc((size_t)E * 4);
    int2*  edges    = (int2*) alloc((size_t)E * 8);
    u32*   hb       = (u32*)  alloc((size_t)N * 32 * 4);   // bf16-packed h
    float* agg      = (float*)alloc((size_t)N * HID * 4);

    hipMemsetAsync(packed, 0, (size_t)N * 8, stream);
    hipMemsetAsync(pooled, 0, (NGRAPH * HID + NGRAPH) * 4, stream);

    int T = (E + 3) / 4;  // threads for histdeg (4 strided edges each)
    histdeg_kernel<<<(T + 255) / 256, 256, 0, stream>>>(dst, ew, packed, rank, E, T);
    unpack_kernel<<<(N + 255) / 256, 256, 0, stream>>>(packed, dinv, count, N);

    int NB = (N + 255) / 256;
    scan_a<<<NB, 256, 0, stream>>>(count, row_ptr, blocksums, N);
    scan_b<<<1, 512, 0, stream>>>(blocksums, NB);
    scan_c<<<NB, 256, 0, stream>>>(row_ptr, blocksums, count, row_end, N);
    fill_kernel<<<(E + 255) / 256, 256, 0, stream>>>(src, dst, ew, dinv, row_ptr, rank, edges, E);

    int gemmBlocks = (N + 63) / 64;
    int rowBlocks = (int)(((size_t)N * 64 + 255) / 256);

    // layer 1
    gemm1_kernel<<<gemmBlocks, 256, 0, stream>>>(x, W1, hb, N);
    agg_kernel<<<rowBlocks, 256, 0, stream>>>(row_ptr, row_end, edges, dinv, hb, agg, N);

    // layer 2
    gemm2_kernel<<<gemmBlocks, 256, 0, stream>>>(agg, b1, W2, hb, N);
    agg_kernel<<<rowBlocks, 256, 0, stream>>>(row_ptr, row_end, edges, dinv, hb, agg, N);

    // pooling
    const int POOL_WAVES = 1024;
    int chunk = (N + POOL_WAVES - 1) / POOL_WAVES;
    pool_kernel<<<POOL_WAVES / 4, 256, 0, stream>>>(agg, bat, pooled, cnt, N, chunk);

    final_kernel<<<(NGRAPH * OUT_DIM + 255) / 256, 256, 0, stream>>>(pooled, cnt, b2, Wfc, bfc, out);
}

// Round 6
// 312.331 us; speedup vs baseline: 6.0498x; 1.3931x over previous
//
#include <hip/hip_runtime.h>

#define IN_DIM 128
#define HID 64
#define OUT_DIM 128
#define NGRAPH 8

#define CHUNK 8192      // edges per chunk for binning passes
#define BSH 9           // 512 nodes per bucket
#define BSZ 512

typedef unsigned long long u64;
typedef unsigned int u32;
typedef __attribute__((ext_vector_type(8))) short short8;   // 8 bf16
typedef __attribute__((ext_vector_type(4))) float f32x4;

__device__ inline short bf16b(float f) {                    // f32 -> bf16 bits
    u32 u = __float_as_uint(f);
    return (short)((u + 0x7FFFu + ((u >> 16) & 1u)) >> 16);
}
__device__ inline u32 pack_bf16(float a, float b) {         // low = a, high = b
    u32 ua = (__float_as_uint(a) + 0x8000u) >> 16;
    u32 ub = (__float_as_uint(b) + 0x8000u) & 0xFFFF0000u;
    return ua | ub;
}
__device__ inline float bf16_lo(u32 v) { return __uint_as_float(v << 16); }
__device__ inline float bf16_hi(u32 v) { return __uint_as_float(v & 0xFFFF0000u); }

// ---- Pass A: per-chunk coarse histogram of dst>>9 (LDS atomics only) -------
__global__ __launch_bounds__(256) void bhist_kernel(const int* __restrict__ dst,
                                                    u32* __restrict__ hist,
                                                    int E, int nchunk, int nbuck) {
    __shared__ u32 h[256];
    for (int i = threadIdx.x; i < 256; i += 256) h[i] = 0;
    __syncthreads();
    int c = blockIdx.x;
    int beg = c * CHUNK, end = min(beg + CHUNK, E);
    for (int i = beg + threadIdx.x; i < end; i += 256)
        atomicAdd(&h[dst[i] >> BSH], 1u);
    __syncthreads();
    for (int b = threadIdx.x; b < nbuck; b += 256)
        hist[(size_t)b * nchunk + c] = h[b];
}

// ---- S1: per bucket, exclusive scan over chunks (in place) + totals --------
__global__ __launch_bounds__(512) void scanS1(u32* __restrict__ hist, u32* __restrict__ tot,
                                              int nchunk, int nbuck) {
    __shared__ u32 sm[512];
    int b = blockIdx.x;
    u32 v = (threadIdx.x < nchunk) ? hist[(size_t)b * nchunk + threadIdx.x] : 0;
    sm[threadIdx.x] = v;
    __syncthreads();
    for (int off = 1; off < 512; off <<= 1) {
        u32 t = (threadIdx.x >= off) ? sm[threadIdx.x - off] : 0;
        __syncthreads();
        sm[threadIdx.x] += t;
        __syncthreads();
    }
    if (threadIdx.x < nchunk) hist[(size_t)b * nchunk + threadIdx.x] = sm[threadIdx.x] - v;
    if (threadIdx.x == 511) tot[b] = sm[511];
}

// ---- S2: exclusive scan over bucket totals -> base[0..nbuck] ---------------
__global__ __launch_bounds__(512) void scanS2(const u32* __restrict__ tot, u32* __restrict__ base,
                                              int nbuck) {
    __shared__ u32 sm[512];
    u32 v = (threadIdx.x < nbuck) ? tot[threadIdx.x] : 0;
    sm[threadIdx.x] = v;
    __syncthreads();
    for (int off = 1; off < 512; off <<= 1) {
        u32 t = (threadIdx.x >= off) ? sm[threadIdx.x - off] : 0;
        __syncthreads();
        sm[threadIdx.x] += t;
        __syncthreads();
    }
    if ((int)threadIdx.x <= nbuck) base[threadIdx.x] = sm[threadIdx.x] - v;
}

// ---- Pass B: scatter edges into bucket-grouped order (LDS cursors) ---------
// record: { src | (dst&511)<<17 , ew_bits }   (src < 2^17)
__global__ __launch_bounds__(256) void bin_kernel(const int* __restrict__ src,
                                                  const int* __restrict__ dst,
                                                  const float* __restrict__ ew,
                                                  const u32* __restrict__ offs,
                                                  const u32* __restrict__ base,
                                                  int2* __restrict__ bse,
                                                  int E, int nchunk, int nbuck) {
    __shared__ u32 cur[256];
    int c = blockIdx.x;
    for (int b = threadIdx.x; b < nbuck; b += 256)
        cur[b] = base[b] + offs[(size_t)b * nchunk + c];
    __syncthreads();
    int beg = c * CHUNK, end = min(beg + CHUNK, E);
    for (int i = beg + threadIdx.x; i < end; i += 256) {
        int d = dst[i];
        int b = d >> BSH;
        u32 slot = atomicAdd(&cur[b], 1u);
        bse[slot] = make_int2(src[i] | ((d & (BSZ - 1)) << 17), __float_as_int(ew[i]));
    }
}

// ---- Pass C: per bucket: fine hist + wdeg (LDS), scan -> row_ptr/dinv, CSR -
__global__ __launch_bounds__(256) void csr_kernel(const int2* __restrict__ bse,
                                                  const u32* __restrict__ base,
                                                  int* __restrict__ row_ptr,
                                                  float* __restrict__ dinv,
                                                  int2* __restrict__ edges, int N) {
    __shared__ u32 cnt[BSZ];
    __shared__ float wdeg[BSZ];
    __shared__ u32 rp[BSZ];
    int b = blockIdx.x;
    int beg = base[b], end = base[b + 1];
    int i0 = threadIdx.x, i1 = threadIdx.x + 256;
    cnt[i0] = 0; cnt[i1] = 0; wdeg[i0] = 0.f; wdeg[i1] = 0.f;
    __syncthreads();
    for (int i = beg + threadIdx.x; i < end; i += 256) {
        int2 e = bse[i];
        int dl = (e.x >> 17) & (BSZ - 1);
        atomicAdd(&cnt[dl], 1u);
        atomicAdd(&wdeg[dl], __int_as_float(e.y));
    }
    __syncthreads();
    // Hillis-Steele inclusive scan over 512 bins, 2 slots/thread
    u32 v0 = cnt[i0], v1 = cnt[i1];
    rp[i0] = v0; rp[i1] = v1;
    __syncthreads();
    for (int off = 1; off < BSZ; off <<= 1) {
        u32 t0 = (i0 >= off) ? rp[i0 - off] : 0;
        u32 t1 = (i1 >= off) ? rp[i1 - off] : 0;
        __syncthreads();
        rp[i0] += t0; rp[i1] += t1;
        __syncthreads();
    }
    int node0 = b * BSZ + i0, node1 = b * BSZ + i1;
    if (node0 <= N) row_ptr[node0] = beg + (int)(rp[i0] - v0);
    if (node1 <= N) row_ptr[node1] = beg + (int)(rp[i1] - v1);
    if (node0 < N) dinv[node0] = rsqrtf(wdeg[i0] + 1.0f);
    if (node1 < N) dinv[node1] = rsqrtf(wdeg[i1] + 1.0f);
    __syncthreads();
    cnt[i0] = rp[i0] - v0;     // reuse cnt as cursor (exclusive prefix)
    cnt[i1] = rp[i1] - v1;
    __syncthreads();
    for (int i = beg + threadIdx.x; i < end; i += 256) {
        int2 e = bse[i];
        int dl = (e.x >> 17) & (BSZ - 1);
        u32 r = atomicAdd(&cnt[dl], 1u);
        edges[beg + r] = make_int2(e.x & 0x1FFFF, e.y);
    }
}

// ---- layer 1 GEMM via MFMA: hb = bf16(dinv[row] * (x @ W1)) ----------------
__global__ __launch_bounds__(256) void gemm1_kernel(const float* __restrict__ x,
                                                    const float* __restrict__ W1,
                                                    const float* __restrict__ dinv,
                                                    u32* __restrict__ hb, int N) {
    int wave = threadIdx.x >> 6, lane = threadIdx.x & 63;
    int col = lane & 15, kg = lane >> 4;
    int rowbase = blockIdx.x * 64 + wave * 16;

    short8 bW[4][4];
#pragma unroll
    for (int ks = 0; ks < 4; ++ks)
#pragma unroll
        for (int nt = 0; nt < 4; ++nt) {
            const float* wp = W1 + (size_t)(ks * 32 + kg * 8) * HID + nt * 16 + col;
            short8 f;
#pragma unroll
            for (int j = 0; j < 8; ++j) f[j] = bf16b(wp[j * HID]);
            bW[ks][nt] = f;
        }

    f32x4 acc[4];
#pragma unroll
    for (int nt = 0; nt < 4; ++nt) acc[nt] = (f32x4){0.f, 0.f, 0.f, 0.f};

    int arow = rowbase + col;
    if (arow >= N) arow = N - 1;
    const float4* xr = reinterpret_cast<const float4*>(x + (size_t)arow * IN_DIM);
#pragma unroll
    for (int ks = 0; ks < 4; ++ks) {
        float4 xa = xr[ks * 8 + kg * 2];
        float4 xb = xr[ks * 8 + kg * 2 + 1];
        short8 a;
        a[0] = bf16b(xa.x); a[1] = bf16b(xa.y); a[2] = bf16b(xa.z); a[3] = bf16b(xa.w);
        a[4] = bf16b(xb.x); a[5] = bf16b(xb.y); a[6] = bf16b(xb.z); a[7] = bf16b(xb.w);
#pragma unroll
        for (int nt = 0; nt < 4; ++nt)
            acc[nt] = __builtin_amdgcn_mfma_f32_16x16x32_bf16(a, bW[ks][nt], acc[nt], 0, 0, 0);
    }

#pragma unroll
    for (int r = 0; r < 4; ++r) {
        int row = rowbase + kg * 4 + r;
        if (row < N) {
            float di = dinv[row];
            hb[(size_t)row * 32 + col]      = pack_bf16(acc[0][r] * di, acc[2][r] * di);
            hb[(size_t)row * 32 + col + 16] = pack_bf16(acc[1][r] * di, acc[3][r] * di);
        }
    }
}

// ---- aggregation: aggb[d] = bf16(dinv[d]*(sum ew*hb[src] + hb[d])) ---------
__global__ void agg_kernel(const int* __restrict__ row_ptr, const int2* __restrict__ edges,
                           const float* __restrict__ dinv, const u32* __restrict__ hb,
                           u32* __restrict__ aggb, int N) {
    int gid = blockIdx.x * blockDim.x + threadIdx.x;
    int node = gid >> 6, lane = gid & 63;
    if (node >= N) return;
    int half = lane >> 5, l = lane & 31;
    int beg = row_ptr[node], end = row_ptr[node + 1];
    int mid = beg + ((end - beg + 1) >> 1);
    int lo = half ? mid : beg;
    int hi = half ? end : mid;
    float ax = 0.f, ay = 0.f;
    if (half == 0) {                        // self-loop: hb already dinv-scaled
        u32 hv = hb[(size_t)node * 32 + l];
        ax = bf16_lo(hv);
        ay = bf16_hi(hv);
    }
    int i = lo;
    for (; i + 8 <= hi; i += 8) {
        int2 e0 = edges[i+0], e1 = edges[i+1], e2 = edges[i+2], e3 = edges[i+3];
        int2 e4 = edges[i+4], e5 = edges[i+5], e6 = edges[i+6], e7 = edges[i+7];
        u32 h0 = hb[(size_t)e0.x * 32 + l], h1 = hb[(size_t)e1.x * 32 + l];
        u32 h2 = hb[(size_t)e2.x * 32 + l], h3 = hb[(size_t)e3.x * 32 + l];
        u32 h4 = hb[(size_t)e4.x * 32 + l], h5 = hb[(size_t)e5.x * 32 + l];
        u32 h6 = hb[(size_t)e6.x * 32 + l], h7 = hb[(size_t)e7.x * 32 + l];
        float c0 = __int_as_float(e0.y), c1 = __int_as_float(e1.y);
        float c2 = __int_as_float(e2.y), c3 = __int_as_float(e3.y);
        float c4 = __int_as_float(e4.y), c5 = __int_as_float(e5.y);
        float c6 = __int_as_float(e6.y), c7 = __int_as_float(e7.y);
        ax += c0 * bf16_lo(h0); ay += c0 * bf16_hi(h0);
        ax += c1 * bf16_lo(h1); ay += c1 * bf16_hi(h1);
        ax += c2 * bf16_lo(h2); ay += c2 * bf16_hi(h2);
        ax += c3 * bf16_lo(h3); ay += c3 * bf16_hi(h3);
        ax += c4 * bf16_lo(h4); ay += c4 * bf16_hi(h4);
        ax += c5 * bf16_lo(h5); ay += c5 * bf16_hi(h5);
        ax += c6 * bf16_lo(h6); ay += c6 * bf16_hi(h6);
        ax += c7 * bf16_lo(h7); ay += c7 * bf16_hi(h7);
    }
    if (i < hi) {                           // predicated tail: full MLP, no serial chain
        int2 e[8];
#pragma unroll
        for (int k = 0; k < 8; ++k) {
            int j = i + k;
            e[k] = edges[j < hi ? j : i];
            if (j >= hi) e[k].y = 0;        // 0.0f coefficient
        }
        u32 hh[8];
#pragma unroll
        for (int k = 0; k < 8; ++k) hh[k] = hb[(size_t)e[k].x * 32 + l];
#pragma unroll
        for (int k = 0; k < 8; ++k) {
            float c = __int_as_float(e[k].y);
            ax += c * bf16_lo(hh[k]);
            ay += c * bf16_hi(hh[k]);
        }
    }
    ax += __shfl_xor(ax, 32);
    ay += __shfl_xor(ay, 32);
    float di = dinv[node];
    if (lane < 32) aggb[(size_t)node * 32 + l] = pack_bf16(di * ax, di * ay);
}

// ---- layer 2 GEMM via MFMA: hb = bf16(dinv[row]*(relu(aggb + b1) @ W2)) ----
__global__ __launch_bounds__(256) void gemm2_kernel(const u32* __restrict__ aggb,
                                                    const float* __restrict__ b1,
                                                    const float* __restrict__ W2,
                                                    const float* __restrict__ dinv,
                                                    u32* __restrict__ hb, int N) {
    int wave = threadIdx.x >> 6, lane = threadIdx.x & 63;
    int col = lane & 15, kg = lane >> 4;
    int rowbase = blockIdx.x * 64 + wave * 16;

    short8 bW[2][4];
#pragma unroll
    for (int ks = 0; ks < 2; ++ks)
#pragma unroll
        for (int nt = 0; nt < 4; ++nt) {
            const float* wp = W2 + (size_t)(ks * 32 + kg * 8) * HID + nt * 16 + col;
            short8 f;
#pragma unroll
            for (int j = 0; j < 8; ++j) f[j] = bf16b(wp[j * HID]);
            bW[ks][nt] = f;
        }

    f32x4 acc[4];
#pragma unroll
    for (int nt = 0; nt < 4; ++nt) acc[nt] = (f32x4){0.f, 0.f, 0.f, 0.f};

    int arow = rowbase + col;
    if (arow >= N) arow = N - 1;
    const u32* ar = aggb + (size_t)arow * 32 + kg * 8;
    u32 w[8];
#pragma unroll
    for (int j = 0; j < 8; ++j) w[j] = ar[j];      // feats (kg*8+j, kg*8+j+32)
#pragma unroll
    for (int ks = 0; ks < 2; ++ks) {
        short8 a;
#pragma unroll
        for (int j = 0; j < 8; ++j) {
            float f = ks ? bf16_hi(w[j]) : bf16_lo(w[j]);
            a[j] = bf16b(fmaxf(f + b1[ks * 32 + kg * 8 + j], 0.f));
        }
#pragma unroll
        for (int nt = 0; nt < 4; ++nt)
            acc[nt] = __builtin_amdgcn_mfma_f32_16x16x32_bf16(a, bW[ks][nt], acc[nt], 0, 0, 0);
    }

#pragma unroll
    for (int r = 0; r < 4; ++r) {
        int row = rowbase + kg * 4 + r;
        if (row < N) {
            float di = dinv[row];
            hb[(size_t)row * 32 + col]      = pack_bf16(acc[0][r] * di, acc[2][r] * di);
            hb[(size_t)row * 32 + col + 16] = pack_bf16(acc[1][r] * di, acc[3][r] * di);
        }
    }
}

// ---- pooling over sorted batch (packed bf16 input) -------------------------
__global__ void pool_kernel(const u32* __restrict__ aggb, const int* __restrict__ batch,
                            float* __restrict__ pooled, float* __restrict__ cnt,
                            int N, int chunk) {
    int wid = (blockIdx.x * blockDim.x + threadIdx.x) >> 6;
    int lane = threadIdx.x & 63;
    int w = lane & 31, hi = lane >> 5;
    int feat = w + hi * 32;
    int start = wid * chunk;
    if (start >= N) return;
    int end = min(start + chunk, N);
    float acc = 0.f, fc = 0.f;
    int cur = batch[start];
    for (int n = start; n < end; ++n) {
        int g = batch[n];
        if (g != cur) {
            atomicAdd(&pooled[cur * HID + feat], acc);
            if (lane == 0) atomicAdd(&cnt[cur], fc);
            cur = g; acc = 0.f; fc = 0.f;
        }
        u32 hv = aggb[(size_t)n * 32 + w];
        acc += hi ? bf16_hi(hv) : bf16_lo(hv);
        fc += 1.f;
    }
    atomicAdd(&pooled[cur * HID + feat], acc);
    if (lane == 0) atomicAdd(&cnt[cur], fc);
}

// ---- final: out = (pooled/cnt + b2) @ Wfc + bfc ----------------------------
__global__ void final_kernel(const float* __restrict__ pooled, const float* __restrict__ cnt,
                             const float* __restrict__ b2, const float* __restrict__ Wfc,
                             const float* __restrict__ bfc, float* __restrict__ out) {
    int idx = blockIdx.x * blockDim.x + threadIdx.x;
    if (idx >= NGRAPH * OUT_DIM) return;
    int g = idx >> 7, o = idx & 127;
    float inv = 1.0f / fmaxf(cnt[g], 1.0f);
    float acc = 0.f;
#pragma unroll
    for (int k = 0; k < HID; ++k)
        acc += (pooled[g * HID + k] * inv + b2[k]) * Wfc[k * OUT_DIM + o];
    out[idx] = acc + bfc[o];
}

extern "C" void kernel_launch(void* const* d_in, const int* in_sizes, int n_in,
                              void* d_out, int out_size, void* d_ws, size_t ws_size,
                              hipStream_t stream) {
    const float* x    = (const float*)d_in[0];
    const int*   ei   = (const int*)d_in[1];
    const float* ew   = (const float*)d_in[2];
    const int*   bat  = (const int*)d_in[3];
    const float* W1   = (const float*)d_in[4];
    const float* b1   = (const float*)d_in[5];
    const float* W2   = (const float*)d_in[6];
    const float* b2   = (const float*)d_in[7];
    const float* Wfc  = (const float*)d_in[8];
    const float* bfc  = (const float*)d_in[9];
    float* out = (float*)d_out;

    const int N = in_sizes[0] / IN_DIM;
    const int E = in_sizes[2];
    const int* src = ei;
    const int* dst = ei + E;

    const int nbuck  = (N + BSZ - 1) >> BSH;        // 196 for N=100000 (<=256 req)
    const int nchunk = (E + CHUNK - 1) / CHUNK;     // 391 for E=3.2M (<=512 req)

    char* ws = (char*)d_ws;
    size_t off = 0;
    auto alloc = [&](size_t bytes) {
        char* p = ws + off;
        off += (bytes + 255) / 256 * 256;
        return p;
    };
    u32*   hist    = (u32*)  alloc((size_t)nbuck * nchunk * 4);
    u32*   tot     = (u32*)  alloc(512 * 4);
    u32*   base    = (u32*)  alloc(512 * 4);
    int*   row_ptr = (int*)  alloc((size_t)(N + 1) * 4);
    float* dinv    = (float*)alloc((size_t)N * 4);
    float* pooled  = (float*)alloc((NGRAPH * HID + NGRAPH) * 4);
    float* cnt     = pooled + NGRAPH * HID;
    int2*  bse     = (int2*) alloc((size_t)E * 8);      // bucket-grouped records
    int2*  edges   = (int2*) alloc((size_t)E * 8);      // final CSR {src, ew}
    u32*   hb      = (u32*)  alloc((size_t)N * 32 * 4); // bf16-packed dinv*h
    u32*   aggb    = (u32*)  alloc((size_t)N * 32 * 4); // bf16-packed agg

    hipMemsetAsync(pooled, 0, (NGRAPH * HID + NGRAPH) * 4, stream);

    // ---- CSR build: zero global atomics ----
    bhist_kernel<<<nchunk, 256, 0, stream>>>(dst, hist, E, nchunk, nbuck);
    scanS1<<<nbuck, 512, 0, stream>>>(hist, tot, nchunk, nbuck);
    scanS2<<<1, 512, 0, stream>>>(tot, base, nbuck);
    bin_kernel<<<nchunk, 256, 0, stream>>>(src, dst, ew, hist, base, bse, E, nchunk, nbuck);
    csr_kernel<<<nbuck, 256, 0, stream>>>(bse, base, row_ptr, dinv, edges, N);

    int gemmBlocks = (N + 63) / 64;
    int rowBlocks = (int)(((size_t)N * 64 + 255) / 256);

    // layer 1
    gemm1_kernel<<<gemmBlocks, 256, 0, stream>>>(x, W1, dinv, hb, N);
    agg_kernel<<<rowBlocks, 256, 0, stream>>>(row_ptr, edges, dinv, hb, aggb, N);

    // layer 2
    gemm2_kernel<<<gemmBlocks, 256, 0, stream>>>(aggb, b1, W2, dinv, hb, N);
    agg_kernel<<<rowBlocks, 256, 0, stream>>>(row_ptr, edges, dinv, hb, aggb, N);

    // pooling
    const int POOL_WAVES = 1024;
    int chunk = (N + POOL_WAVES - 1) / POOL_WAVES;
    pool_kernel<<<POOL_WAVES / 4, 256, 0, stream>>>(aggb, bat, pooled, cnt, N, chunk);

    final_kernel<<<(NGRAPH * OUT_DIM + 255) / 256, 256, 0, stream>>>(pooled, cnt, b2, Wfc, bfc, out);
}

// Round 7
// 301.646 us; speedup vs baseline: 6.2641x; 1.0354x over previous
//
#include <hip/hip_runtime.h>

#define IN_DIM 128
#define HID 64
#define OUT_DIM 128
#define NGRAPH 8

#define CHUNK 4096      // edges per chunk for binning passes
#define BSH 9           // 512 nodes per bucket
#define BSZ 512

typedef unsigned long long u64;
typedef unsigned int u32;
typedef __attribute__((ext_vector_type(8))) short short8;   // 8 bf16
typedef __attribute__((ext_vector_type(4))) float f32x4;

__device__ inline short bf16b(float f) {                    // f32 -> bf16 bits
    u32 u = __float_as_uint(f);
    return (short)((u + 0x7FFFu + ((u >> 16) & 1u)) >> 16);
}
__device__ inline u32 pack_bf16(float a, float b) {         // low = a, high = b
    u32 ua = (__float_as_uint(a) + 0x8000u) >> 16;
    u32 ub = (__float_as_uint(b) + 0x8000u) & 0xFFFF0000u;
    return ua | ub;
}
__device__ inline float bf16_lo(u32 v) { return __uint_as_float(v << 16); }
__device__ inline float bf16_hi(u32 v) { return __uint_as_float(v & 0xFFFF0000u); }

// ---- Pass A: per-chunk coarse histogram of dst>>9 (LDS atomics only) -------
__global__ __launch_bounds__(256) void bhist_kernel(const int* __restrict__ dst,
                                                    u32* __restrict__ hist,
                                                    int E, int nchunk, int nbuck) {
    __shared__ u32 h[256];
    h[threadIdx.x] = 0;
    __syncthreads();
    int c = blockIdx.x;
    int beg = c * CHUNK, end = min(beg + CHUNK, E);
    for (int i = beg + threadIdx.x; i < end; i += 256)
        atomicAdd(&h[dst[i] >> BSH], 1u);
    __syncthreads();
    for (int b = threadIdx.x; b < nbuck; b += 256)
        hist[(size_t)b * nchunk + c] = h[b];
}

// ---- S1: per bucket, exclusive scan over chunks (<=1024, 2/thread) ---------
__global__ __launch_bounds__(512) void scanS1(u32* __restrict__ hist, u32* __restrict__ tot,
                                              int nchunk, int nbuck) {
    __shared__ u32 sm[1024];
    int b = blockIdx.x;
    int i0 = threadIdx.x, i1 = threadIdx.x + 512;
    u32 v0 = (i0 < nchunk) ? hist[(size_t)b * nchunk + i0] : 0;
    u32 v1 = (i1 < nchunk) ? hist[(size_t)b * nchunk + i1] : 0;
    sm[i0] = v0; sm[i1] = v1;
    __syncthreads();
    for (int off = 1; off < 1024; off <<= 1) {
        u32 t0 = (i0 >= off) ? sm[i0 - off] : 0;
        u32 t1 = (i1 >= off) ? sm[i1 - off] : 0;
        __syncthreads();
        sm[i0] += t0; sm[i1] += t1;
        __syncthreads();
    }
    if (i0 < nchunk) hist[(size_t)b * nchunk + i0] = sm[i0] - v0;
    if (i1 < nchunk) hist[(size_t)b * nchunk + i1] = sm[i1] - v1;
    if (threadIdx.x == 511) tot[b] = sm[1023];
}

// ---- S2: exclusive scan over bucket totals -> base[0..nbuck] ---------------
__global__ __launch_bounds__(512) void scanS2(const u32* __restrict__ tot, u32* __restrict__ base,
                                              int nbuck) {
    __shared__ u32 sm[512];
    u32 v = (threadIdx.x < nbuck) ? tot[threadIdx.x] : 0;
    sm[threadIdx.x] = v;
    __syncthreads();
    for (int off = 1; off < 512; off <<= 1) {
        u32 t = (threadIdx.x >= off) ? sm[threadIdx.x - off] : 0;
        __syncthreads();
        sm[threadIdx.x] += t;
        __syncthreads();
    }
    if ((int)threadIdx.x <= nbuck) base[threadIdx.x] = sm[threadIdx.x] - v;
}

// ---- Pass B: LDS counting-sort per chunk, then COALESCED write-out ---------
// record: { src | (dst&511)<<17 , ew_bits }   (src < 2^17)
__global__ __launch_bounds__(256) void bin_kernel(const int* __restrict__ src,
                                                  const int* __restrict__ dst,
                                                  const float* __restrict__ ew,
                                                  const u32* __restrict__ offs,
                                                  const u32* __restrict__ base,
                                                  int2* __restrict__ bse,
                                                  int E, int nchunk, int nbuck) {
    __shared__ u32 lcnt[256];                 // per-bucket count, then cursor
    __shared__ u32 lpos[256];                 // exclusive local offsets
    __shared__ u32 gbase[256];                // global target base for this chunk
    __shared__ int2 buf[CHUNK];               // bucket-sorted records (32 KB)
    __shared__ unsigned char bb[CHUNK];       // bucket id per sorted slot

    int c = blockIdx.x;
    int beg = c * CHUNK, end = min(beg + CHUNK, E);
    lcnt[threadIdx.x] = 0;
    __syncthreads();
    // pass 1: count buckets
    for (int i = beg + threadIdx.x; i < end; i += 256)
        atomicAdd(&lcnt[dst[i] >> BSH], 1u);
    __syncthreads();
    // exclusive scan of 256 counts (Hillis-Steele in LDS)
    u32 v = lcnt[threadIdx.x];
    lpos[threadIdx.x] = v;
    __syncthreads();
    for (int off = 1; off < 256; off <<= 1) {
        u32 t = (threadIdx.x >= off) ? lpos[threadIdx.x - off] : 0;
        __syncthreads();
        lpos[threadIdx.x] += t;
        __syncthreads();
    }
    u32 excl = lpos[threadIdx.x] - v;
    __syncthreads();
    lpos[threadIdx.x] = excl;                 // exclusive prefix
    lcnt[threadIdx.x] = excl;                 // running cursor
    if (threadIdx.x < (u32)nbuck)
        gbase[threadIdx.x] = base[threadIdx.x] + offs[(size_t)threadIdx.x * nchunk + c];
    __syncthreads();
    // pass 2: scatter into LDS in bucket order
    for (int i = beg + threadIdx.x; i < end; i += 256) {
        int d = dst[i];
        int b = d >> BSH;
        u32 p = atomicAdd(&lcnt[b], 1u);
        buf[p] = make_int2(src[i] | ((d & (BSZ - 1)) << 17), __float_as_int(ew[i]));
        bb[p] = (unsigned char)b;
    }
    __syncthreads();
    // write-out: slot j of bucket b -> bse[gbase[b] + j - lpos[b]] (coalesced runs)
    int tot = end - beg;
    for (int j = threadIdx.x; j < tot; j += 256) {
        int b = bb[j];
        bse[gbase[b] + j - lpos[b]] = buf[j];
    }
}

// ---- Pass C: per bucket: fine hist + wdeg (LDS), scan -> row_ptr/dinv, CSR -
__global__ __launch_bounds__(256) void csr_kernel(const int2* __restrict__ bse,
                                                  const u32* __restrict__ base,
                                                  int* __restrict__ row_ptr,
                                                  float* __restrict__ dinv,
                                                  int2* __restrict__ edges, int N) {
    __shared__ u32 cnt[BSZ];
    __shared__ float wdeg[BSZ];
    __shared__ u32 rp[BSZ];
    int b = blockIdx.x;
    int beg = base[b], end = base[b + 1];
    int i0 = threadIdx.x, i1 = threadIdx.x + 256;
    cnt[i0] = 0; cnt[i1] = 0; wdeg[i0] = 0.f; wdeg[i1] = 0.f;
    __syncthreads();
    for (int i = beg + threadIdx.x; i < end; i += 256) {
        int2 e = bse[i];
        int dl = (e.x >> 17) & (BSZ - 1);
        atomicAdd(&cnt[dl], 1u);
        atomicAdd(&wdeg[dl], __int_as_float(e.y));
    }
    __syncthreads();
    u32 v0 = cnt[i0], v1 = cnt[i1];
    rp[i0] = v0; rp[i1] = v1;
    __syncthreads();
    for (int off = 1; off < BSZ; off <<= 1) {
        u32 t0 = (i0 >= off) ? rp[i0 - off] : 0;
        u32 t1 = (i1 >= off) ? rp[i1 - off] : 0;
        __syncthreads();
        rp[i0] += t0; rp[i1] += t1;
        __syncthreads();
    }
    int node0 = b * BSZ + i0, node1 = b * BSZ + i1;
    if (node0 <= N) row_ptr[node0] = beg + (int)(rp[i0] - v0);
    if (node1 <= N) row_ptr[node1] = beg + (int)(rp[i1] - v1);
    if (node0 < N) dinv[node0] = rsqrtf(wdeg[i0] + 1.0f);
    if (node1 < N) dinv[node1] = rsqrtf(wdeg[i1] + 1.0f);
    __syncthreads();
    cnt[i0] = rp[i0] - v0;     // reuse cnt as cursor (exclusive prefix)
    cnt[i1] = rp[i1] - v1;
    __syncthreads();
    for (int i = beg + threadIdx.x; i < end; i += 256) {
        int2 e = bse[i];
        int dl = (e.x >> 17) & (BSZ - 1);
        u32 r = atomicAdd(&cnt[dl], 1u);
        edges[beg + r] = make_int2(e.x & 0x1FFFF, e.y);
    }
}

// ---- layer 1 GEMM via MFMA: hb = bf16(dinv[row] * (x @ W1)) ----------------
__global__ __launch_bounds__(256) void gemm1_kernel(const float* __restrict__ x,
                                                    const float* __restrict__ W1,
                                                    const float* __restrict__ dinv,
                                                    u32* __restrict__ hb, int N) {
    int wave = threadIdx.x >> 6, lane = threadIdx.x & 63;
    int col = lane & 15, kg = lane >> 4;
    int rowbase = blockIdx.x * 64 + wave * 16;

    short8 bW[4][4];
#pragma unroll
    for (int ks = 0; ks < 4; ++ks)
#pragma unroll
        for (int nt = 0; nt < 4; ++nt) {
            const float* wp = W1 + (size_t)(ks * 32 + kg * 8) * HID + nt * 16 + col;
            short8 f;
#pragma unroll
            for (int j = 0; j < 8; ++j) f[j] = bf16b(wp[j * HID]);
            bW[ks][nt] = f;
        }

    f32x4 acc[4];
#pragma unroll
    for (int nt = 0; nt < 4; ++nt) acc[nt] = (f32x4){0.f, 0.f, 0.f, 0.f};

    int arow = rowbase + col;
    if (arow >= N) arow = N - 1;
    const float4* xr = reinterpret_cast<const float4*>(x + (size_t)arow * IN_DIM);
#pragma unroll
    for (int ks = 0; ks < 4; ++ks) {
        float4 xa = xr[ks * 8 + kg * 2];
        float4 xb = xr[ks * 8 + kg * 2 + 1];
        short8 a;
        a[0] = bf16b(xa.x); a[1] = bf16b(xa.y); a[2] = bf16b(xa.z); a[3] = bf16b(xa.w);
        a[4] = bf16b(xb.x); a[5] = bf16b(xb.y); a[6] = bf16b(xb.z); a[7] = bf16b(xb.w);
#pragma unroll
        for (int nt = 0; nt < 4; ++nt)
            acc[nt] = __builtin_amdgcn_mfma_f32_16x16x32_bf16(a, bW[ks][nt], acc[nt], 0, 0, 0);
    }

#pragma unroll
    for (int r = 0; r < 4; ++r) {
        int row = rowbase + kg * 4 + r;
        if (row < N) {
            float di = dinv[row];
            hb[(size_t)row * 32 + col]      = pack_bf16(acc[0][r] * di, acc[2][r] * di);
            hb[(size_t)row * 32 + col + 16] = pack_bf16(acc[1][r] * di, acc[3][r] * di);
        }
    }
}

// ---- aggregation: aggb[d] = bf16(dinv[d]*(sum ew*hb[src] + hb[d])) ---------
__global__ void agg_kernel(const int* __restrict__ row_ptr, const int2* __restrict__ edges,
                           const float* __restrict__ dinv, const u32* __restrict__ hb,
                           u32* __restrict__ aggb, int N) {
    int gid = blockIdx.x * blockDim.x + threadIdx.x;
    int node = gid >> 6, lane = gid & 63;
    if (node >= N) return;
    int half = lane >> 5, l = lane & 31;
    int beg = row_ptr[node], end = row_ptr[node + 1];
    int mid = beg + ((end - beg + 1) >> 1);
    int lo = half ? mid : beg;
    int hi = half ? end : mid;
    float ax = 0.f, ay = 0.f;
    if (half == 0) {                        // self-loop: hb already dinv-scaled
        u32 hv = hb[(size_t)node * 32 + l];
        ax = bf16_lo(hv);
        ay = bf16_hi(hv);
    }
    int i = lo;
    for (; i + 8 <= hi; i += 8) {
        int2 e0 = edges[i+0], e1 = edges[i+1], e2 = edges[i+2], e3 = edges[i+3];
        int2 e4 = edges[i+4], e5 = edges[i+5], e6 = edges[i+6], e7 = edges[i+7];
        u32 h0 = hb[(size_t)e0.x * 32 + l], h1 = hb[(size_t)e1.x * 32 + l];
        u32 h2 = hb[(size_t)e2.x * 32 + l], h3 = hb[(size_t)e3.x * 32 + l];
        u32 h4 = hb[(size_t)e4.x * 32 + l], h5 = hb[(size_t)e5.x * 32 + l];
        u32 h6 = hb[(size_t)e6.x * 32 + l], h7 = hb[(size_t)e7.x * 32 + l];
        float c0 = __int_as_float(e0.y), c1 = __int_as_float(e1.y);
        float c2 = __int_as_float(e2.y), c3 = __int_as_float(e3.y);
        float c4 = __int_as_float(e4.y), c5 = __int_as_float(e5.y);
        float c6 = __int_as_float(e6.y), c7 = __int_as_float(e7.y);
        ax += c0 * bf16_lo(h0); ay += c0 * bf16_hi(h0);
        ax += c1 * bf16_lo(h1); ay += c1 * bf16_hi(h1);
        ax += c2 * bf16_lo(h2); ay += c2 * bf16_hi(h2);
        ax += c3 * bf16_lo(h3); ay += c3 * bf16_hi(h3);
        ax += c4 * bf16_lo(h4); ay += c4 * bf16_hi(h4);
        ax += c5 * bf16_lo(h5); ay += c5 * bf16_hi(h5);
        ax += c6 * bf16_lo(h6); ay += c6 * bf16_hi(h6);
        ax += c7 * bf16_lo(h7); ay += c7 * bf16_hi(h7);
    }
    if (i < hi) {                           // predicated tail: full MLP, no serial chain
        int2 e[8];
#pragma unroll
        for (int k = 0; k < 8; ++k) {
            int j = i + k;
            e[k] = edges[j < hi ? j : i];
            if (j >= hi) e[k].y = 0;        // 0.0f coefficient
        }
        u32 hh[8];
#pragma unroll
        for (int k = 0; k < 8; ++k) hh[k] = hb[(size_t)e[k].x * 32 + l];
#pragma unroll
        for (int k = 0; k < 8; ++k) {
            float c = __int_as_float(e[k].y);
            ax += c * bf16_lo(hh[k]);
            ay += c * bf16_hi(hh[k]);
        }
    }
    ax += __shfl_xor(ax, 32);
    ay += __shfl_xor(ay, 32);
    float di = dinv[node];
    if (lane < 32) aggb[(size_t)node * 32 + l] = pack_bf16(di * ax, di * ay);
}

// ---- layer 2 GEMM via MFMA: hb = bf16(dinv[row]*(relu(aggb + b1) @ W2)) ----
__global__ __launch_bounds__(256) void gemm2_kernel(const u32* __restrict__ aggb,
                                                    const float* __restrict__ b1,
                                                    const float* __restrict__ W2,
                                                    const float* __restrict__ dinv,
                                                    u32* __restrict__ hb, int N) {
    int wave = threadIdx.x >> 6, lane = threadIdx.x & 63;
    int col = lane & 15, kg = lane >> 4;
    int rowbase = blockIdx.x * 64 + wave * 16;

    short8 bW[2][4];
#pragma unroll
    for (int ks = 0; ks < 2; ++ks)
#pragma unroll
        for (int nt = 0; nt < 4; ++nt) {
            const float* wp = W2 + (size_t)(ks * 32 + kg * 8) * HID + nt * 16 + col;
            short8 f;
#pragma unroll
            for (int j = 0; j < 8; ++j) f[j] = bf16b(wp[j * HID]);
            bW[ks][nt] = f;
        }

    f32x4 acc[4];
#pragma unroll
    for (int nt = 0; nt < 4; ++nt) acc[nt] = (f32x4){0.f, 0.f, 0.f, 0.f};

    int arow = rowbase + col;
    if (arow >= N) arow = N - 1;
    const u32* ar = aggb + (size_t)arow * 32 + kg * 8;
    u32 w[8];
#pragma unroll
    for (int j = 0; j < 8; ++j) w[j] = ar[j];      // feats (kg*8+j, kg*8+j+32)
#pragma unroll
    for (int ks = 0; ks < 2; ++ks) {
        short8 a;
#pragma unroll
        for (int j = 0; j < 8; ++j) {
            float f = ks ? bf16_hi(w[j]) : bf16_lo(w[j]);
            a[j] = bf16b(fmaxf(f + b1[ks * 32 + kg * 8 + j], 0.f));
        }
#pragma unroll
        for (int nt = 0; nt < 4; ++nt)
            acc[nt] = __builtin_amdgcn_mfma_f32_16x16x32_bf16(a, bW[ks][nt], acc[nt], 0, 0, 0);
    }

#pragma unroll
    for (int r = 0; r < 4; ++r) {
        int row = rowbase + kg * 4 + r;
        if (row < N) {
            float di = dinv[row];
            hb[(size_t)row * 32 + col]      = pack_bf16(acc[0][r] * di, acc[2][r] * di);
            hb[(size_t)row * 32 + col + 16] = pack_bf16(acc[1][r] * di, acc[3][r] * di);
        }
    }
}

// ---- pooling over sorted batch (packed bf16 input) -------------------------
__global__ void pool_kernel(const u32* __restrict__ aggb, const int* __restrict__ batch,
                            float* __restrict__ pooled, float* __restrict__ cnt,
                            int N, int chunk) {
    int wid = (blockIdx.x * blockDim.x + threadIdx.x) >> 6;
    int lane = threadIdx.x & 63;
    int w = lane & 31, hi = lane >> 5;
    int feat = w + hi * 32;
    int start = wid * chunk;
    if (start >= N) return;
    int end = min(start + chunk, N);
    float acc = 0.f, fc = 0.f;
    int cur = batch[start];
    for (int n = start; n < end; ++n) {
        int g = batch[n];
        if (g != cur) {
            atomicAdd(&pooled[cur * HID + feat], acc);
            if (lane == 0) atomicAdd(&cnt[cur], fc);
            cur = g; acc = 0.f; fc = 0.f;
        }
        u32 hv = aggb[(size_t)n * 32 + w];
        acc += hi ? bf16_hi(hv) : bf16_lo(hv);
        fc += 1.f;
    }
    atomicAdd(&pooled[cur * HID + feat], acc);
    if (lane == 0) atomicAdd(&cnt[cur], fc);
}

// ---- final: out = (pooled/cnt + b2) @ Wfc + bfc ----------------------------
__global__ void final_kernel(const float* __restrict__ pooled, const float* __restrict__ cnt,
                             const float* __restrict__ b2, const float* __restrict__ Wfc,
                             const float* __restrict__ bfc, float* __restrict__ out) {
    int idx = blockIdx.x * blockDim.x + threadIdx.x;
    if (idx >= NGRAPH * OUT_DIM) return;
    int g = idx >> 7, o = idx & 127;
    float inv = 1.0f / fmaxf(cnt[g], 1.0f);
    float acc = 0.f;
#pragma unroll
    for (int k = 0; k < HID; ++k)
        acc += (pooled[g * HID + k] * inv + b2[k]) * Wfc[k * OUT_DIM + o];
    out[idx] = acc + bfc[o];
}

extern "C" void kernel_launch(void* const* d_in, const int* in_sizes, int n_in,
                              void* d_out, int out_size, void* d_ws, size_t ws_size,
                              hipStream_t stream) {
    const float* x    = (const float*)d_in[0];
    const int*   ei   = (const int*)d_in[1];
    const float* ew   = (const float*)d_in[2];
    const int*   bat  = (const int*)d_in[3];
    const float* W1   = (const float*)d_in[4];
    const float* b1   = (const float*)d_in[5];
    const float* W2   = (const float*)d_in[6];
    const float* b2   = (const float*)d_in[7];
    const float* Wfc  = (const float*)d_in[8];
    const float* bfc  = (const float*)d_in[9];
    float* out = (float*)d_out;

    const int N = in_sizes[0] / IN_DIM;
    const int E = in_sizes[2];
    const int* src = ei;
    const int* dst = ei + E;

    const int nbuck  = (N + BSZ - 1) >> BSH;        // 196 for N=100000 (<=256 req)
    const int nchunk = (E + CHUNK - 1) / CHUNK;     // 782 for E=3.2M (<=1024 req)

    char* ws = (char*)d_ws;
    size_t off = 0;
    auto alloc = [&](size_t bytes) {
        char* p = ws + off;
        off += (bytes + 255) / 256 * 256;
        return p;
    };
    u32*   hist    = (u32*)  alloc((size_t)nbuck * nchunk * 4);
    u32*   tot     = (u32*)  alloc(512 * 4);
    u32*   base    = (u32*)  alloc(512 * 4);
    int*   row_ptr = (int*)  alloc((size_t)(N + 1) * 4);
    float* dinv    = (float*)alloc((size_t)N * 4);
    float* pooled  = (float*)alloc((NGRAPH * HID + NGRAPH) * 4);
    float* cnt     = pooled + NGRAPH * HID;
    int2*  bse     = (int2*) alloc((size_t)E * 8);      // bucket-grouped records
    int2*  edges   = (int2*) alloc((size_t)E * 8);      // final CSR {src, ew}
    u32*   hb      = (u32*)  alloc((size_t)N * 32 * 4); // bf16-packed dinv*h
    u32*   aggb    = (u32*)  alloc((size_t)N * 32 * 4); // bf16-packed agg

    hipMemsetAsync(pooled, 0, (NGRAPH * HID + NGRAPH) * 4, stream);

    // ---- CSR build: zero global atomics, coalesced scatter ----
    bhist_kernel<<<nchunk, 256, 0, stream>>>(dst, hist, E, nchunk, nbuck);
    scanS1<<<nbuck, 512, 0, stream>>>(hist, tot, nchunk, nbuck);
    scanS2<<<1, 512, 0, stream>>>(tot, base, nbuck);
    bin_kernel<<<nchunk, 256, 0, stream>>>(src, dst, ew, hist, base, bse, E, nchunk, nbuck);
    csr_kernel<<<nbuck, 256, 0, stream>>>(bse, base, row_ptr, dinv, edges, N);

    int gemmBlocks = (N + 63) / 64;
    int rowBlocks = (int)(((size_t)N * 64 + 255) / 256);

    // layer 1
    gemm1_kernel<<<gemmBlocks, 256, 0, stream>>>(x, W1, dinv, hb, N);
    agg_kernel<<<rowBlocks, 256, 0, stream>>>(row_ptr, edges, dinv, hb, aggb, N);

    // layer 2
    gemm2_kernel<<<gemmBlocks, 256, 0, stream>>>(aggb, b1, W2, dinv, hb, N);
    agg_kernel<<<rowBlocks, 256, 0, stream>>>(row_ptr, edges, dinv, hb, aggb, N);

    // pooling
    const int POOL_WAVES = 1024;
    int chunk = (N + POOL_WAVES - 1) / POOL_WAVES;
    pool_kernel<<<POOL_WAVES / 4, 256, 0, stream>>>(aggb, bat, pooled, cnt, N, chunk);

    final_kernel<<<(NGRAPH * OUT_DIM + 255) / 256, 256, 0, stream>>>(pooled, cnt, b2, Wfc, bfc, out);
}